// Round 3
// baseline (1044.436 us; speedup 1.0000x reference)
//
#include <hip/hip_runtime.h>
#include <math.h>

#define D      512
#define BQ     128
#define KK     3
#define THR    0.15f
#define SSCALE 5.0f
#define BN     128
#define SENT   0x7fffffff

using bf16x8 = __attribute__((ext_vector_type(8))) short;
using f32x4  = __attribute__((ext_vector_type(4))) float;

__device__ __forceinline__ unsigned short f2bf(float x) {
    unsigned u = __float_as_uint(x);
    return (unsigned short)((u + 0x7fffu + ((u >> 16) & 1u)) >> 16);
}

// tie-aware top-4 insert (descending, lower index wins ties) — matches jax.lax.top_k
__device__ __forceinline__ void ins4(float v, int c,
                                     float& v0, float& v1, float& v2, float& v3,
                                     int& c0, int& c1, int& c2, int& c3) {
    bool b0 = (v > v0) || (v == v0 && c < c0);
    bool b1 = (v > v1) || (v == v1 && c < c1);
    bool b2 = (v > v2) || (v == v2 && c < c2);
    bool b3 = (v > v3) || (v == v3 && c < c3);
    if (b0)      { v3=v2; c3=c2; v2=v1; c2=c1; v1=v0; c1=c0; v0=v; c0=c; }
    else if (b1) { v3=v2; c3=c2; v2=v1; c2=c1; v1=v;  c1=c; }
    else if (b2) { v3=v2; c3=c2; v2=v;  c2=c; }
    else if (b3) { v3=v;  c3=c; }
}

template<int K>
__device__ __forceinline__ void insK(float v, int c, float* V, int* C) {
    #pragma unroll
    for (int k = 0; k < K; ++k) {
        if (v > V[k] || (v == V[k] && c < C[k])) {
            #pragma unroll
            for (int m = K - 1; m > k; --m) { V[m] = V[m-1]; C[m] = C[m-1]; }
            V[k] = v; C[k] = c;
            return;
        }
    }
}

// ---------------- kernel 1: normalize i_feats + build A fragment image ----------------
// apre slot layout: slot = ((c*2+ks)*4 + kg)*128 + row, 16B/slot (8 bf16),
// holding ihat[row][k = c*64 + ks*32 + kg*8 .. +8].  (slot == l*128 + row for thread l)
__global__ void prep_kernel(const float* __restrict__ x, float* __restrict__ ihat,
                            uint4* __restrict__ apre) {
    int r = blockIdx.x;
    int l = threadIdx.x;             // 0..63, owns k = l*8 .. l*8+7
    const float4* row = (const float4*)(x + (size_t)r * D);
    float4 v0 = row[l * 2 + 0];
    float4 v1 = row[l * 2 + 1];
    float s = v0.x*v0.x + v0.y*v0.y + v0.z*v0.z + v0.w*v0.w
            + v1.x*v1.x + v1.y*v1.y + v1.z*v1.z + v1.w*v1.w;
    #pragma unroll
    for (int off = 32; off > 0; off >>= 1) s += __shfl_xor(s, off);
    float inv = 1.0f / sqrtf(s);
    float a0 = v0.x*inv, a1 = v0.y*inv, a2 = v0.z*inv, a3 = v0.w*inv;
    float a4 = v1.x*inv, a5 = v1.y*inv, a6 = v1.z*inv, a7 = v1.w*inv;
    float4* orow = (float4*)(ihat + (size_t)r * D);
    orow[l*2+0] = make_float4(a0, a1, a2, a3);
    orow[l*2+1] = make_float4(a4, a5, a6, a7);
    uint4 p;
    p.x = f2bf(a0) | ((unsigned)f2bf(a1) << 16);
    p.y = f2bf(a2) | ((unsigned)f2bf(a3) << 16);
    p.z = f2bf(a4) | ((unsigned)f2bf(a5) << 16);
    p.w = f2bf(a6) | ((unsigned)f2bf(a7) << 16);
    apre[l * 128 + r] = p;
}

// ---------------- kernel 2: MFMA sim + in-register per-block top-4 ----------------
// 512 threads = 8 waves; wave w owns A-rows [16w,16w+16). B tile (128 cols x 64 k bf16)
// double-buffered in LDS with XOR swizzle. A frags streamed from apre (L2-hot).
__global__ __launch_bounds__(512, 2)
void sim_topk_kernel(const uint4* __restrict__ apre, const float* __restrict__ img,
                     int N, int nb4, float* __restrict__ pv, int* __restrict__ pi)
{
    __shared__ unsigned char ldsB[2][16384];
    __shared__ float sums[128];

    const int tid  = threadIdx.x;
    const int lane = tid & 63;
    const int wid  = tid >> 6;
    const int lr   = lane & 15;
    const int kg   = lane >> 4;

    const int col_t = tid >> 2;            // 0..127: this thread's staging column
    const int sp    = tid & 3;             // 16-float sub-slot within the 64-k chunk
    const int c_base = blockIdx.x * BN;

    // B staging LDS byte offsets (two 16B writes per chunk), XOR-swizzled
    const int wsw = (col_t & 7) << 4;
    const int wb0 = col_t * 128 + (((sp * 32) + 0)  ^ wsw);
    const int wb1 = col_t * 128 + (((sp * 32) + 16) ^ wsw);

    const int gcol = c_base + col_t;
    const bool ok  = gcol < N;
    const float* gsrc = img + (size_t)(ok ? gcol : 0) * D + sp * 16;

    // A-frag source pointer (fragment-ordered image)
    const int arow = wid * 16 + lr;
    const uint4* asrc = apre + kg * 128 + arow;

    // B-frag read offsets: (nf*16+lr)*128 + ((ks*64 + kg*16) ^ ((lr&7)<<4))
    const int rsw = (lr & 7) << 4;
    const int in0 = (kg * 16)      ^ rsw;   // ks = 0
    const int in1 = (64 + kg * 16) ^ rsw;   // ks = 1
    int b_row[8];
    #pragma unroll
    for (int nf = 0; nf < 8; ++nf) b_row[nf] = (nf * 16 + lr) * 128;

    f32x4 acc[8];
    #pragma unroll
    for (int nf = 0; nf < 8; ++nf) acc[nf] = (f32x4){0.f, 0.f, 0.f, 0.f};
    float sq = 0.f;

    float4  rB[2][4];
    bf16x8  rA[2][2];

#define LOADC(cc, pb)                                                          \
    do {                                                                       \
        const float* s_ = gsrc + (cc) * 64;                                    \
        if (ok) {                                                              \
            rB[pb][0] = *(const float4*)(s_ + 0);                              \
            rB[pb][1] = *(const float4*)(s_ + 4);                              \
            rB[pb][2] = *(const float4*)(s_ + 8);                              \
            rB[pb][3] = *(const float4*)(s_ + 12);                             \
        } else {                                                               \
            rB[pb][0] = make_float4(0.f,0.f,0.f,0.f);                          \
            rB[pb][1] = make_float4(0.f,0.f,0.f,0.f);                          \
            rB[pb][2] = make_float4(0.f,0.f,0.f,0.f);                          \
            rB[pb][3] = make_float4(0.f,0.f,0.f,0.f);                          \
        }                                                                      \
        rA[pb][0] = *(const bf16x8*)(asrc + ((cc)*2 + 0) * 512);               \
        rA[pb][1] = *(const bf16x8*)(asrc + ((cc)*2 + 1) * 512);               \
    } while (0)

#define PROCC(pb)                                                              \
    do {                                                                       \
        float4 u0 = rB[pb][0], u1 = rB[pb][1], u2 = rB[pb][2], u3 = rB[pb][3]; \
        sq += u0.x*u0.x + u0.y*u0.y + u0.z*u0.z + u0.w*u0.w                    \
            + u1.x*u1.x + u1.y*u1.y + u1.z*u1.z + u1.w*u1.w                    \
            + u2.x*u2.x + u2.y*u2.y + u2.z*u2.z + u2.w*u2.w                    \
            + u3.x*u3.x + u3.y*u3.y + u3.z*u3.z + u3.w*u3.w;                   \
        uint4 p0, p1;                                                          \
        p0.x = f2bf(u0.x) | ((unsigned)f2bf(u0.y) << 16);                      \
        p0.y = f2bf(u0.z) | ((unsigned)f2bf(u0.w) << 16);                      \
        p0.z = f2bf(u1.x) | ((unsigned)f2bf(u1.y) << 16);                      \
        p0.w = f2bf(u1.z) | ((unsigned)f2bf(u1.w) << 16);                      \
        p1.x = f2bf(u2.x) | ((unsigned)f2bf(u2.y) << 16);                      \
        p1.y = f2bf(u2.z) | ((unsigned)f2bf(u2.w) << 16);                      \
        p1.z = f2bf(u3.x) | ((unsigned)f2bf(u3.y) << 16);                      \
        p1.w = f2bf(u3.z) | ((unsigned)f2bf(u3.w) << 16);                      \
        *(uint4*)(&ldsB[pb][wb0]) = p0;                                        \
        *(uint4*)(&ldsB[pb][wb1]) = p1;                                        \
    } while (0)

#define MFMAC(pb)                                                              \
    do {                                                                       \
        const unsigned char* B_ = ldsB[pb];                                    \
        bf16x8 a0 = rA[pb][0], a1 = rA[pb][1];                                 \
        _Pragma("unroll")                                                      \
        for (int nf = 0; nf < 8; ++nf) {                                       \
            bf16x8 b0 = *(const bf16x8*)(B_ + b_row[nf] + in0);                \
            acc[nf] = __builtin_amdgcn_mfma_f32_16x16x32_bf16(a0, b0, acc[nf], 0, 0, 0); \
        }                                                                      \
        _Pragma("unroll")                                                      \
        for (int nf = 0; nf < 8; ++nf) {                                       \
            bf16x8 b1 = *(const bf16x8*)(B_ + b_row[nf] + in1);                \
            acc[nf] = __builtin_amdgcn_mfma_f32_16x16x32_bf16(a1, b1, acc[nf], 0, 0, 0); \
        }                                                                      \
    } while (0)

    LOADC(0, 0);
    PROCC(0);
    __syncthreads();

    #pragma unroll
    for (int c = 0; c < 8; ++c) {
        const int pb = c & 1;
        const int nx = pb ^ 1;
        if (c < 7) LOADC(c + 1, nx);
        MFMAC(pb);
        if (c < 7) PROCC(nx);
        __syncthreads();
    }

    // column sumsq: reduce across the 4 staging lanes of each column
    sq += __shfl_xor(sq, 1);
    sq += __shfl_xor(sq, 2);
    if (sp == 0) sums[col_t] = sq;
    __syncthreads();

    // in-register top-4 per row, then 16-lane butterfly merge
    float iv[8]; int cn[8];
    #pragma unroll
    for (int nf = 0; nf < 8; ++nf) {
        int col = nf * 16 + lr;
        float ss = sums[col];
        iv[nf] = ss > 0.f ? rsqrtf(ss) : 0.f;
        cn[nf] = c_base + col;
    }

    #pragma unroll
    for (int r = 0; r < 4; ++r) {
        float v0=-1e30f, v1=-1e30f, v2=-1e30f, v3=-1e30f;
        int   c0=SENT, c1=SENT, c2=SENT, c3=SENT;
        #pragma unroll
        for (int nf = 0; nf < 8; ++nf) {
            if (cn[nf] < N)
                ins4(acc[nf][r] * iv[nf], cn[nf], v0,v1,v2,v3, c0,c1,c2,c3);
        }
        #pragma unroll
        for (int off = 1; off <= 8; off <<= 1) {
            float mv0 = __shfl_xor(v0, off), mv1 = __shfl_xor(v1, off);
            float mv2 = __shfl_xor(v2, off), mv3 = __shfl_xor(v3, off);
            int   mc0 = __shfl_xor(c0, off), mc1 = __shfl_xor(c1, off);
            int   mc2 = __shfl_xor(c2, off), mc3 = __shfl_xor(c3, off);
            ins4(mv0, mc0, v0,v1,v2,v3, c0,c1,c2,c3);
            ins4(mv1, mc1, v0,v1,v2,v3, c0,c1,c2,c3);
            ins4(mv2, mc2, v0,v1,v2,v3, c0,c1,c2,c3);
            ins4(mv3, mc3, v0,v1,v2,v3, c0,c1,c2,c3);
        }
        if (lr == 0) {
            int row = wid * 16 + kg * 4 + r;
            size_t base = (size_t)row * nb4 + (size_t)blockIdx.x * 4;
            pv[base+0] = v0; pv[base+1] = v1; pv[base+2] = v2; pv[base+3] = v3;
            pi[base+0] = c0; pi[base+1] = c1; pi[base+2] = c2; pi[base+3] = c3;
        }
    }
#undef LOADC
#undef PROCC
#undef MFMAC
}

// ---------------- kernel 3: reduce partials -> top-8 -> exact rescore -> weights ----
__global__ __launch_bounds__(256)
void reduce_rescore(const float* __restrict__ pv, const int* __restrict__ pi, int nb4,
                    const float* __restrict__ ihat, const float* __restrict__ img,
                    float* __restrict__ swo, int* __restrict__ sidxo,
                    int* __restrict__ valido)
{
    __shared__ float lv[256][8];
    __shared__ int   li[256][8];
    __shared__ float sv[8];
    __shared__ int   si[8];
    const int r = blockIdx.x, tid = threadIdx.x;

    float V[8]; int C[8];
    #pragma unroll
    for (int k = 0; k < 8; ++k) { V[k] = -1e30f; C[k] = SENT; }
    const float* prow = pv + (size_t)r * nb4;
    const int*   irow = pi + (size_t)r * nb4;
    for (int j = tid; j < nb4; j += 256) {
        int c = irow[j];
        if (c != SENT) insK<8>(prow[j], c, V, C);
    }
    #pragma unroll
    for (int k = 0; k < 8; ++k) { lv[tid][k] = V[k]; li[tid][k] = C[k]; }
    __syncthreads();
    if (tid < 16) {
        for (int o = 1; o < 16; ++o) {
            int t2 = tid + o * 16;
            #pragma unroll
            for (int s = 0; s < 8; ++s)
                if (li[t2][s] != SENT) insK<8>(lv[t2][s], li[t2][s], V, C);
        }
        #pragma unroll
        for (int k = 0; k < 8; ++k) { lv[tid][k] = V[k]; li[tid][k] = C[k]; }
    }
    __syncthreads();
    if (tid == 0) {
        for (int o = 1; o < 16; ++o)
            #pragma unroll
            for (int s = 0; s < 8; ++s)
                if (li[o][s] != SENT) insK<8>(lv[o][s], li[o][s], V, C);
        #pragma unroll
        for (int k = 0; k < 8; ++k) si[k] = C[k];
    }
    __syncthreads();

    // exact fp32 rescore of the 8 candidates (32 lanes each)
    {
        const int k = tid >> 5, l = tid & 31;
        int idx = si[k];
        float dot = 0.f, ssq = 0.f;
        if (idx != SENT) {
            const float* a = ihat + (size_t)r * D + l * 16;
            const float* b = img + (size_t)idx * D + l * 16;
            #pragma unroll
            for (int j = 0; j < 4; ++j) {
                float4 va = *(const float4*)(a + j*4);
                float4 vb = *(const float4*)(b + j*4);
                dot += va.x*vb.x + va.y*vb.y + va.z*vb.z + va.w*vb.w;
                ssq += vb.x*vb.x + vb.y*vb.y + vb.z*vb.z + vb.w*vb.w;
            }
        }
        #pragma unroll
        for (int o = 16; o > 0; o >>= 1) { dot += __shfl_xor(dot, o); ssq += __shfl_xor(ssq, o); }
        if (l == 0) sv[k] = (idx != SENT && ssq > 0.f) ? dot * rsqrtf(ssq) : -1e30f;
    }
    __syncthreads();

    if (tid == 0) {
        float Vt[4]; int Ct[4];
        #pragma unroll
        for (int k = 0; k < 4; ++k) { Vt[k] = -1e30f; Ct[k] = SENT; }
        #pragma unroll
        for (int k = 0; k < 8; ++k)
            if (si[k] != SENT) insK<4>(sv[k], si[k], Vt, Ct);
        float lg[4]; int vd[3];
        lg[0] = SSCALE;
        #pragma unroll
        for (int k = 0; k < 3; ++k) {
            vd[k] = (Vt[k+1] > THR) ? 1 : 0;
            lg[k+1] = vd[k] ? SSCALE * Vt[k+1] : -1e30f;
        }
        float m = fmaxf(fmaxf(lg[0], lg[1]), fmaxf(lg[2], lg[3]));
        float e0 = expf(lg[0]-m), e1 = expf(lg[1]-m), e2 = expf(lg[2]-m), e3 = expf(lg[3]-m);
        float sum = e0 + e1 + e2 + e3;
        float ee[3] = {e1, e2, e3};
        #pragma unroll
        for (int k = 0; k < 3; ++k) {
            float w = 1.0f - ee[k] / sum;
            swo[r*3+k]    = vd[k] ? w : 0.0f;
            sidxo[r*3+k]  = vd[k] ? Ct[k+1] : 0;
            valido[r*3+k] = vd[k];
        }
    }
}

// ---------------- kernel 4: assemble output (1536 x 512 fp32) ----------------
__global__ void assemble_kernel(const float* __restrict__ i_feats, const float* __restrict__ t_feats,
                                const float* __restrict__ img, const float* __restrict__ txt,
                                const float* __restrict__ sw, const int* __restrict__ sidx,
                                const int* __restrict__ valid, float* __restrict__ out)
{
    const int r = blockIdx.x;      // 0..1535
    const int t = threadIdx.x;     // 0..127
    float4* orow = (float4*)(out + (size_t)r * D);
    if (r < 128) {
        orow[t] = ((const float4*)(i_feats + (size_t)r * D))[t];
    } else if (r < 512) {
        int s = r - 128;
        float4 v = make_float4(0.f,0.f,0.f,0.f);
        if (valid[s]) v = ((const float4*)(img + (size_t)sidx[s] * D))[t];
        orow[t] = v;
    } else if (r < 640) {
        orow[t] = ((const float4*)(t_feats + (size_t)(r - 512) * D))[t];
    } else if (r < 1024) {
        int s = r - 640;
        float4 v = make_float4(0.f,0.f,0.f,0.f);
        if (valid[s]) v = ((const float4*)(txt + (size_t)sidx[s] * D))[t];
        orow[t] = v;
    } else {
        int li = r - 1024;
        float o[4];
        int j0 = t * 4;
        if (li < 128) {
            #pragma unroll
            for (int u = 0; u < 4; ++u) {
                int j = j0 + u;
                if (j < 128) o[u] = (j == li) ? 1.0f : 0.0f;
                else {
                    int s = j - 128;
                    o[u] = (s / 3 == li) ? sw[li*3 + (s % 3)] : 0.0f;
                }
            }
        } else {
            int i2 = li - 128;
            int b = i2 / 3;
            int vi = valid[i2];
            #pragma unroll
            for (int u = 0; u < 4; ++u) {
                int j = j0 + u;
                float val;
                if (j < 128) val = (vi && j == b) ? 1.0f : 0.0f;
                else {
                    int s2 = j - 128;
                    int vj = valid[s2];
                    int b2 = s2 / 3;
                    if (vi && vj)        val = (b == b2) ? 1.0f : 0.0f;
                    else if (!vi && !vj) val = (i2 == s2) ? 1.0f : 0.0f;
                    else                 val = 0.0f;
                }
                o[u] = val;
            }
        }
        orow[t] = make_float4(o[0], o[1], o[2], o[3]);
    }
}

extern "C" void kernel_launch(void* const* d_in, const int* in_sizes, int n_in,
                              void* d_out, int out_size, void* d_ws, size_t ws_size,
                              hipStream_t stream) {
    const float* i_feats = (const float*)d_in[0];
    const float* t_feats = (const float*)d_in[1];
    const float* img     = (const float*)d_in[2];
    const float* txt     = (const float*)d_in[3];
    float* out = (float*)d_out;

    const int N   = in_sizes[2] / D;           // 200000
    const int nb  = (N + BN - 1) / BN;         // 1563
    const int nb4 = nb * 4;

    char* ws = (char*)d_ws;
    size_t off = 0;
    float* ihat = (float*)(ws + off); off += (size_t)BQ * D * 4;          // 256 KB
    uint4* apre = (uint4*)(ws + off); off += (size_t)BQ * D * 2;          // 128 KB
    float* pv   = (float*)(ws + off); off += (size_t)BQ * nb4 * 4;        // 3.2 MB
    int*   pi   = (int*)(ws + off);   off += (size_t)BQ * nb4 * 4;        // 3.2 MB
    float* swv  = (float*)(ws + off); off += BQ * 4 * 4;
    int*   sidx = (int*)(ws + off);   off += BQ * 4 * 4;
    int*   vld  = (int*)(ws + off);   off += BQ * 4 * 4;

    prep_kernel<<<BQ, 64, 0, stream>>>(i_feats, ihat, apre);
    sim_topk_kernel<<<nb, 512, 0, stream>>>(apre, img, N, nb4, pv, pi);
    reduce_rescore<<<BQ, 256, 0, stream>>>(pv, pi, nb4, ihat, img, swv, sidx, vld);
    assemble_kernel<<<3 * (BQ + BQ * KK), 128, 0, stream>>>(i_feats, t_feats, img, txt,
                                                            swv, sidx, vld, out);
}

// Round 5
// 857.970 us; speedup vs baseline: 1.2173x; 1.2173x over previous
//
#include <hip/hip_runtime.h>
#include <hip/hip_bf16.h>
#include <math.h>

#define D      512
#define BQ     128
#define KK     3
#define THR    0.15f
#define SSCALE 5.0f
#define SENT   0x7fffffff
#define NBLK   512
#define WPB    8
#define NWAVES (NBLK * WPB)
#define NB4    (NBLK * 4)

using bf16x8 = __attribute__((ext_vector_type(8))) short;
using f32x4  = __attribute__((ext_vector_type(4))) float;

__device__ __forceinline__ unsigned short f2bf(float x) {
    unsigned u = __float_as_uint(x);
    return (unsigned short)((u + 0x7fffu + ((u >> 16) & 1u)) >> 16);
}

__device__ __forceinline__ unsigned pk2(float lo, float hi) {
    __hip_bfloat162 h = __float22bfloat162_rn(make_float2(lo, hi));
    union { __hip_bfloat162 h; unsigned u; } c; c.h = h;
    return c.u;
}

__device__ __forceinline__ bf16x8 cvt8(float4 f0, float4 f1) {
    union { unsigned u[4]; bf16x8 v; } r;
    r.u[0] = pk2(f0.x, f0.y);
    r.u[1] = pk2(f0.z, f0.w);
    r.u[2] = pk2(f1.x, f1.y);
    r.u[3] = pk2(f1.z, f1.w);
    return r.v;
}

// tie-aware top-4 insert (descending, lower index wins ties) — matches jax.lax.top_k
__device__ __forceinline__ void ins4a(float v, int c, float V[4], int C[4]) {
    bool b0 = (v > V[0]) || (v == V[0] && c < C[0]);
    bool b1 = (v > V[1]) || (v == V[1] && c < C[1]);
    bool b2 = (v > V[2]) || (v == V[2] && c < C[2]);
    bool b3 = (v > V[3]) || (v == V[3] && c < C[3]);
    if (b0)      { V[3]=V[2]; C[3]=C[2]; V[2]=V[1]; C[2]=C[1]; V[1]=V[0]; C[1]=C[0]; V[0]=v; C[0]=c; }
    else if (b1) { V[3]=V[2]; C[3]=C[2]; V[2]=V[1]; C[2]=C[1]; V[1]=v;  C[1]=c; }
    else if (b2) { V[3]=V[2]; C[3]=C[2]; V[2]=v;  C[2]=c; }
    else if (b3) { V[3]=v;  C[3]=c; }
}

template<int K>
__device__ __forceinline__ void insK(float v, int c, float* V, int* C) {
    #pragma unroll
    for (int k = 0; k < K; ++k) {
        if (v > V[k] || (v == V[k] && c < C[k])) {
            #pragma unroll
            for (int m = K - 1; m > k; --m) { V[m] = V[m-1]; C[m] = C[m-1]; }
            V[k] = v; C[k] = c;
            return;
        }
    }
}

// ---------------- kernel 1: normalize i_feats + query bf16 fragment image ----------------
// apre slot = q*64 + c*4 + g (16B each): bf16 of ihat[q][k], k = c*32 + g*8 .. +8
__global__ void prep_kernel(const float* __restrict__ x, float* __restrict__ ihat,
                            uint4* __restrict__ apre) {
    int r = blockIdx.x;
    int l = threadIdx.x;             // 0..63, owns k = l*8 .. +8  (c = l>>2, g = l&3)
    const float4* row = (const float4*)(x + (size_t)r * D);
    float4 v0 = row[l * 2 + 0];
    float4 v1 = row[l * 2 + 1];
    float s = v0.x*v0.x + v0.y*v0.y + v0.z*v0.z + v0.w*v0.w
            + v1.x*v1.x + v1.y*v1.y + v1.z*v1.z + v1.w*v1.w;
    #pragma unroll
    for (int off = 32; off > 0; off >>= 1) s += __shfl_xor(s, off);
    float inv = 1.0f / sqrtf(s);
    float a0 = v0.x*inv, a1 = v0.y*inv, a2 = v0.z*inv, a3 = v0.w*inv;
    float a4 = v1.x*inv, a5 = v1.y*inv, a6 = v1.z*inv, a7 = v1.w*inv;
    float4* orow = (float4*)(ihat + (size_t)r * D);
    orow[l*2+0] = make_float4(a0, a1, a2, a3);
    orow[l*2+1] = make_float4(a4, a5, a6, a7);
    uint4 p;
    p.x = f2bf(a0) | ((unsigned)f2bf(a1) << 16);
    p.y = f2bf(a2) | ((unsigned)f2bf(a3) << 16);
    p.z = f2bf(a4) | ((unsigned)f2bf(a5) << 16);
    p.w = f2bf(a6) | ((unsigned)f2bf(a7) << 16);
    apre[r * 64 + l] = p;
}

// ---------------- kernel 2: barrier-free streaming MFMA sim + per-wave top-4 ----------------
// Queries (B operand) in LDS [c:16][q:128][64B]. Swizzle XOR uses ONLY bits 4-5
// ((q&3)<<4): bijective within each 64-byte (q,c) row. (R4 bug: (q&7)<<4 carried
// bit 6 out of the row -> queries q%8==3 and q%8==4 collided.)
// Each wave streams 16-img-row tiles (grid-stride), A-frags direct from global,
// 4-chunk register prefetch, zero barriers in the hot loop.
__global__ __launch_bounds__(512, 2)
void sim_topk(const uint4* __restrict__ apre, const float* __restrict__ img,
              int N, int ntiles, float* __restrict__ pv, int* __restrict__ pi)
{
    extern __shared__ __align__(16) unsigned char Bs[];   // 131072 B
    const int tid  = threadIdx.x;
    const int lane = tid & 63;
    const int wid  = tid >> 6;
    const int lr   = lane & 15;
    const int kg   = lane >> 4;

    // stage query frags -> swizzled LDS (one-time)
    #pragma unroll
    for (int j = 0; j < 16; ++j) {
        int s = tid + j * 512;                 // 0..8191
        uint4 p = apre[s];
        int q = s >> 6, c = (s >> 2) & 15, g = s & 3;
        int addr = c * 8192 + q * 64 + ((g * 16) ^ ((q & 3) << 4));
        *(uint4*)(Bs + addr) = p;
    }
    __syncthreads();

    // frag(nf, c) = Bs + c*8192 + nf*1024 + lane_off
    const int lane_off = lr * 64 + ((kg * 16) ^ ((lr & 3) << 4));

    // per-lane running top-4 for 8 queries (q = nf*16 + lr)
    float lv[8][4]; int lc[8][4];
    #pragma unroll
    for (int nf = 0; nf < 8; ++nf)
        #pragma unroll
        for (int s = 0; s < 4; ++s) { lv[nf][s] = -1e30f; lc[nf][s] = SENT; }

    const int gwave = blockIdx.x * WPB + wid;
    int t = gwave;
    const float* gp;
    {
        int row = t * 16 + lr;
        if (row >= N) row = N - 1;
        gp = img + (size_t)row * D + kg * 8;
    }

    float4 pre[4][2];
    if (t < ntiles) {
        #pragma unroll
        for (int c = 0; c < 4; ++c) {
            pre[c][0] = *(const float4*)(gp + c * 32);
            pre[c][1] = *(const float4*)(gp + c * 32 + 4);
        }
    }

#define CHUNK(c) do {                                                          \
        float4 f0_ = pre[(c) & 3][0], f1_ = pre[(c) & 3][1];                   \
        if ((c) < 12) {                                                        \
            pre[(c) & 3][0] = *(const float4*)(gp + ((c) + 4) * 32);           \
            pre[(c) & 3][1] = *(const float4*)(gp + ((c) + 4) * 32 + 4);       \
        } else {                                                               \
            pre[(c) & 3][0] = *(const float4*)(gpn + ((c) - 12) * 32);         \
            pre[(c) & 3][1] = *(const float4*)(gpn + ((c) - 12) * 32 + 4);     \
        }                                                                      \
        sq += f0_.x*f0_.x + f0_.y*f0_.y + f0_.z*f0_.z + f0_.w*f0_.w            \
            + f1_.x*f1_.x + f1_.y*f1_.y + f1_.z*f1_.z + f1_.w*f1_.w;           \
        bf16x8 a_ = cvt8(f0_, f1_);                                            \
        const unsigned char* bp_ = Bs + (c) * 8192 + lane_off;                 \
        _Pragma("unroll")                                                      \
        for (int nf_ = 0; nf_ < 8; ++nf_) {                                    \
            bf16x8 b_ = *(const bf16x8*)(bp_ + nf_ * 1024);                    \
            acc[nf_] = __builtin_amdgcn_mfma_f32_16x16x32_bf16(a_, b_, acc[nf_], 0, 0, 0); \
        }                                                                      \
    } while (0)

    while (t < ntiles) {
        int tn = t + NWAVES;
        const float* gpn;
        {
            int tt = (tn < ntiles) ? tn : t;
            int row = tt * 16 + lr;
            if (row >= N) row = N - 1;
            gpn = img + (size_t)row * D + kg * 8;
        }
        f32x4 acc[8];
        #pragma unroll
        for (int nf = 0; nf < 8; ++nf) acc[nf] = (f32x4){0.f, 0.f, 0.f, 0.f};
        float sq = 0.f;

        CHUNK(0);  CHUNK(1);  CHUNK(2);  CHUNK(3);
        CHUNK(4);  CHUNK(5);  CHUNK(6);  CHUNK(7);
        CHUNK(8);  CHUNK(9);  CHUNK(10); CHUNK(11);
        CHUNK(12); CHUNK(13); CHUNK(14); CHUNK(15);

        // row norms: lane's sq covers its row's kg-slices; butterfly over kg lanes
        float s2 = sq;
        s2 += __shfl_xor(s2, 16);
        s2 += __shfl_xor(s2, 32);
        float rnorm = s2 > 0.f ? rsqrtf(s2) : 0.f;
        float rn[4];
        #pragma unroll
        for (int g = 0; g < 4; ++g) rn[g] = __shfl(rnorm, kg * 4 + g);

        const int ib = t * 16 + kg * 4;
        #pragma unroll
        for (int nf = 0; nf < 8; ++nf) {
            #pragma unroll
            for (int g = 0; g < 4; ++g) {
                int idx = ib + g;
                if (idx < N) ins4a(acc[nf][g] * rn[g], idx, lv[nf], lc[nf]);
            }
        }
        t = tn; gp = gpn;
    }
#undef CHUNK

    // merge across the 4 kg lane-groups (same query lives in lanes lr, lr+16, lr+32, lr+48)
    #pragma unroll
    for (int nf = 0; nf < 8; ++nf) {
        #pragma unroll
        for (int st = 0; st < 2; ++st) {
            const int off = st ? 32 : 16;
            float mv[4]; int mc[4];
            #pragma unroll
            for (int s = 0; s < 4; ++s) {
                mv[s] = __shfl_xor(lv[nf][s], off);
                mc[s] = __shfl_xor(lc[nf][s], off);
            }
            #pragma unroll
            for (int s = 0; s < 4; ++s) ins4a(mv[s], mc[s], lv[nf], lc[nf]);
        }
    }

    // block-level merge in LDS (query buffer dead now)
    __syncthreads();
    if (kg == 0) {
        #pragma unroll
        for (int nf = 0; nf < 8; ++nf) {
            int q = nf * 16 + lr;
            float* mv = (float*)(Bs + ((size_t)wid * 128 + q) * 32);
            int*   mi = (int*)(mv + 4);
            #pragma unroll
            for (int s = 0; s < 4; ++s) { mv[s] = lv[nf][s]; mi[s] = lc[nf][s]; }
        }
    }
    __syncthreads();
    if (tid < BQ) {
        int q = tid;
        float V[4]; int C[4];
        #pragma unroll
        for (int s = 0; s < 4; ++s) { V[s] = -1e30f; C[s] = SENT; }
        for (int w = 0; w < WPB; ++w) {
            const float* mv = (const float*)(Bs + ((size_t)w * 128 + q) * 32);
            const int*   mi = (const int*)(mv + 4);
            #pragma unroll
            for (int s = 0; s < 4; ++s)
                if (mi[s] != SENT) ins4a(mv[s], mi[s], V, C);
        }
        size_t base = (size_t)q * NB4 + (size_t)blockIdx.x * 4;
        #pragma unroll
        for (int s = 0; s < 4; ++s) { pv[base + s] = V[s]; pi[base + s] = C[s]; }
    }
}

// ---------------- kernel 3: reduce partials -> top-8 -> exact rescore -> weights ----
__global__ __launch_bounds__(256)
void reduce_rescore(const float* __restrict__ pv, const int* __restrict__ pi, int nb4,
                    const float* __restrict__ ihat, const float* __restrict__ img,
                    float* __restrict__ swo, int* __restrict__ sidxo,
                    int* __restrict__ valido)
{
    __shared__ float lv[256][8];
    __shared__ int   li[256][8];
    __shared__ float sv[8];
    __shared__ int   si[8];
    const int r = blockIdx.x, tid = threadIdx.x;

    float V[8]; int C[8];
    #pragma unroll
    for (int k = 0; k < 8; ++k) { V[k] = -1e30f; C[k] = SENT; }
    const float* prow = pv + (size_t)r * nb4;
    const int*   irow = pi + (size_t)r * nb4;
    for (int j = tid; j < nb4; j += 256) {
        int c = irow[j];
        if (c != SENT) insK<8>(prow[j], c, V, C);
    }
    #pragma unroll
    for (int k = 0; k < 8; ++k) { lv[tid][k] = V[k]; li[tid][k] = C[k]; }
    __syncthreads();
    if (tid < 16) {
        for (int o = 1; o < 16; ++o) {
            int t2 = tid + o * 16;
            #pragma unroll
            for (int s = 0; s < 8; ++s)
                if (li[t2][s] != SENT) insK<8>(lv[t2][s], li[t2][s], V, C);
        }
        #pragma unroll
        for (int k = 0; k < 8; ++k) { lv[tid][k] = V[k]; li[tid][k] = C[k]; }
    }
    __syncthreads();
    if (tid == 0) {
        for (int o = 1; o < 16; ++o)
            #pragma unroll
            for (int s = 0; s < 8; ++s)
                if (li[o][s] != SENT) insK<8>(lv[o][s], li[o][s], V, C);
        #pragma unroll
        for (int k = 0; k < 8; ++k) si[k] = C[k];
    }
    __syncthreads();

    // exact fp32 rescore of the 8 candidates (32 lanes each)
    {
        const int k = tid >> 5, l = tid & 31;
        int idx = si[k];
        float dot = 0.f, ssq = 0.f;
        if (idx != SENT) {
            const float* a = ihat + (size_t)r * D + l * 16;
            const float* b = img + (size_t)idx * D + l * 16;
            #pragma unroll
            for (int j = 0; j < 4; ++j) {
                float4 va = *(const float4*)(a + j*4);
                float4 vb = *(const float4*)(b + j*4);
                dot += va.x*vb.x + va.y*vb.y + va.z*vb.z + va.w*vb.w;
                ssq += vb.x*vb.x + vb.y*vb.y + vb.z*vb.z + vb.w*vb.w;
            }
        }
        #pragma unroll
        for (int o = 16; o > 0; o >>= 1) { dot += __shfl_xor(dot, o); ssq += __shfl_xor(ssq, o); }
        if (l == 0) sv[k] = (idx != SENT && ssq > 0.f) ? dot * rsqrtf(ssq) : -1e30f;
    }
    __syncthreads();

    if (tid == 0) {
        float Vt[4]; int Ct[4];
        #pragma unroll
        for (int k = 0; k < 4; ++k) { Vt[k] = -1e30f; Ct[k] = SENT; }
        #pragma unroll
        for (int k = 0; k < 8; ++k)
            if (si[k] != SENT) insK<4>(sv[k], si[k], Vt, Ct);
        float lg[4]; int vd[3];
        lg[0] = SSCALE;
        #pragma unroll
        for (int k = 0; k < 3; ++k) {
            vd[k] = (Vt[k+1] > THR) ? 1 : 0;
            lg[k+1] = vd[k] ? SSCALE * Vt[k+1] : -1e30f;
        }
        float m = fmaxf(fmaxf(lg[0], lg[1]), fmaxf(lg[2], lg[3]));
        float e0 = expf(lg[0]-m), e1 = expf(lg[1]-m), e2 = expf(lg[2]-m), e3 = expf(lg[3]-m);
        float sum = e0 + e1 + e2 + e3;
        float ee[3] = {e1, e2, e3};
        #pragma unroll
        for (int k = 0; k < 3; ++k) {
            float w = 1.0f - ee[k] / sum;
            swo[r*3+k]    = vd[k] ? w : 0.0f;
            sidxo[r*3+k]  = vd[k] ? Ct[k+1] : 0;
            valido[r*3+k] = vd[k];
        }
    }
}

// ---------------- kernel 4: assemble output (1536 x 512 fp32) ----------------
__global__ void assemble_kernel(const float* __restrict__ i_feats, const float* __restrict__ t_feats,
                                const float* __restrict__ img, const float* __restrict__ txt,
                                const float* __restrict__ sw, const int* __restrict__ sidx,
                                const int* __restrict__ valid, float* __restrict__ out)
{
    const int r = blockIdx.x;      // 0..1535
    const int t = threadIdx.x;     // 0..127
    float4* orow = (float4*)(out + (size_t)r * D);
    if (r < 128) {
        orow[t] = ((const float4*)(i_feats + (size_t)r * D))[t];
    } else if (r < 512) {
        int s = r - 128;
        float4 v = make_float4(0.f,0.f,0.f,0.f);
        if (valid[s]) v = ((const float4*)(img + (size_t)sidx[s] * D))[t];
        orow[t] = v;
    } else if (r < 640) {
        orow[t] = ((const float4*)(t_feats + (size_t)(r - 512) * D))[t];
    } else if (r < 1024) {
        int s = r - 640;
        float4 v = make_float4(0.f,0.f,0.f,0.f);
        if (valid[s]) v = ((const float4*)(txt + (size_t)sidx[s] * D))[t];
        orow[t] = v;
    } else {
        int li = r - 1024;
        float o[4];
        int j0 = t * 4;
        if (li < 128) {
            #pragma unroll
            for (int u = 0; u < 4; ++u) {
                int j = j0 + u;
                if (j < 128) o[u] = (j == li) ? 1.0f : 0.0f;
                else {
                    int s = j - 128;
                    o[u] = (s / 3 == li) ? sw[li*3 + (s % 3)] : 0.0f;
                }
            }
        } else {
            int i2 = li - 128;
            int b = i2 / 3;
            int vi = valid[i2];
            #pragma unroll
            for (int u = 0; u < 4; ++u) {
                int j = j0 + u;
                float val;
                if (j < 128) val = (vi && j == b) ? 1.0f : 0.0f;
                else {
                    int s2 = j - 128;
                    int vj = valid[s2];
                    int b2 = s2 / 3;
                    if (vi && vj)        val = (b == b2) ? 1.0f : 0.0f;
                    else if (!vi && !vj) val = (i2 == s2) ? 1.0f : 0.0f;
                    else                 val = 0.0f;
                }
                o[u] = val;
            }
        }
        orow[t] = make_float4(o[0], o[1], o[2], o[3]);
    }
}

extern "C" void kernel_launch(void* const* d_in, const int* in_sizes, int n_in,
                              void* d_out, int out_size, void* d_ws, size_t ws_size,
                              hipStream_t stream) {
    const float* i_feats = (const float*)d_in[0];
    const float* t_feats = (const float*)d_in[1];
    const float* img     = (const float*)d_in[2];
    const float* txt     = (const float*)d_in[3];
    float* out = (float*)d_out;

    const int N      = in_sizes[2] / D;        // 200000
    const int ntiles = (N + 15) / 16;          // 12500

    char* ws = (char*)d_ws;
    size_t off = 0;
    float* ihat = (float*)(ws + off); off += (size_t)BQ * D * 4;          // 256 KB
    uint4* apre = (uint4*)(ws + off); off += (size_t)BQ * D * 2;          // 128 KB
    float* pv   = (float*)(ws + off); off += (size_t)BQ * NB4 * 4;        // 1 MB
    int*   pi   = (int*)(ws + off);   off += (size_t)BQ * NB4 * 4;        // 1 MB
    float* swv  = (float*)(ws + off); off += BQ * 4 * 4;
    int*   sidx = (int*)(ws + off);   off += BQ * 4 * 4;
    int*   vld  = (int*)(ws + off);   off += BQ * 4 * 4;

    prep_kernel<<<BQ, 64, 0, stream>>>(i_feats, ihat, apre);
    sim_topk<<<NBLK, 512, 131072, stream>>>(apre, img, N, ntiles, pv, pi);
    reduce_rescore<<<BQ, 256, 0, stream>>>(pv, pi, NB4, ihat, img, swv, sidx, vld);
    assemble_kernel<<<3 * (BQ + BQ * KK), 128, 0, stream>>>(i_feats, t_feats, img, txt,
                                                            swv, sidx, vld, out);
}

// Round 6
// 710.868 us; speedup vs baseline: 1.4692x; 1.2069x over previous
//
#include <hip/hip_runtime.h>
#include <hip/hip_bf16.h>
#include <math.h>

#define D      512
#define BQ     128
#define KK     3
#define THR    0.15f
#define SSCALE 5.0f
#define SENT   0x7fffffff
#define NBLK   256
#define WPB    8
#define NWAVES (NBLK * WPB)
#define NB4    (NBLK * 4)

using bf16x8 = __attribute__((ext_vector_type(8))) short;
using f32x4  = __attribute__((ext_vector_type(4))) float;

__device__ __forceinline__ unsigned short f2bf(float x) {
    unsigned u = __float_as_uint(x);
    return (unsigned short)((u + 0x7fffu + ((u >> 16) & 1u)) >> 16);
}

__device__ __forceinline__ unsigned pk2(float lo, float hi) {
    __hip_bfloat162 h = __float22bfloat162_rn(make_float2(lo, hi));
    union { __hip_bfloat162 h; unsigned u; } c; c.h = h;
    return c.u;
}

__device__ __forceinline__ bf16x8 cvt8(float4 f0, float4 f1) {
    union { unsigned u[4]; bf16x8 v; } r;
    r.u[0] = pk2(f0.x, f0.y);
    r.u[1] = pk2(f0.z, f0.w);
    r.u[2] = pk2(f1.x, f1.y);
    r.u[3] = pk2(f1.z, f1.w);
    return r.v;
}

// tie-aware top-4 insert (descending, lower index wins ties) — matches jax.lax.top_k
__device__ __forceinline__ void ins4a(float v, int c, float V[4], int C[4]) {
    bool b0 = (v > V[0]) || (v == V[0] && c < C[0]);
    bool b1 = (v > V[1]) || (v == V[1] && c < C[1]);
    bool b2 = (v > V[2]) || (v == V[2] && c < C[2]);
    bool b3 = (v > V[3]) || (v == V[3] && c < C[3]);
    if (b0)      { V[3]=V[2]; C[3]=C[2]; V[2]=V[1]; C[2]=C[1]; V[1]=V[0]; C[1]=C[0]; V[0]=v; C[0]=c; }
    else if (b1) { V[3]=V[2]; C[3]=C[2]; V[2]=V[1]; C[2]=C[1]; V[1]=v;  C[1]=c; }
    else if (b2) { V[3]=V[2]; C[3]=C[2]; V[2]=v;  C[2]=c; }
    else if (b3) { V[3]=v;  C[3]=c; }
}

template<int K>
__device__ __forceinline__ void insK(float v, int c, float* V, int* C) {
    #pragma unroll
    for (int k = 0; k < K; ++k) {
        if (v > V[k] || (v == V[k] && c < C[k])) {
            #pragma unroll
            for (int m = K - 1; m > k; --m) { V[m] = V[m-1]; C[m] = C[m-1]; }
            V[k] = v; C[k] = c;
            return;
        }
    }
}

// ---------------- kernel 1: normalize i_feats + query bf16 fragment image ----------------
// apre slot = q*64 + c*4 + g (16B each): bf16 of ihat[q][k], k = c*32 + g*8 .. +8
__global__ void prep_kernel(const float* __restrict__ x, float* __restrict__ ihat,
                            uint4* __restrict__ apre) {
    int r = blockIdx.x;
    int l = threadIdx.x;             // 0..63, owns k = l*8 .. +8  (c = l>>2, g = l&3)
    const float4* row = (const float4*)(x + (size_t)r * D);
    float4 v0 = row[l * 2 + 0];
    float4 v1 = row[l * 2 + 1];
    float s = v0.x*v0.x + v0.y*v0.y + v0.z*v0.z + v0.w*v0.w
            + v1.x*v1.x + v1.y*v1.y + v1.z*v1.z + v1.w*v1.w;
    #pragma unroll
    for (int off = 32; off > 0; off >>= 1) s += __shfl_xor(s, off);
    float inv = 1.0f / sqrtf(s);
    float a0 = v0.x*inv, a1 = v0.y*inv, a2 = v0.z*inv, a3 = v0.w*inv;
    float a4 = v1.x*inv, a5 = v1.y*inv, a6 = v1.z*inv, a7 = v1.w*inv;
    float4* orow = (float4*)(ihat + (size_t)r * D);
    orow[l*2+0] = make_float4(a0, a1, a2, a3);
    orow[l*2+1] = make_float4(a4, a5, a6, a7);
    uint4 p;
    p.x = f2bf(a0) | ((unsigned)f2bf(a1) << 16);
    p.y = f2bf(a2) | ((unsigned)f2bf(a3) << 16);
    p.z = f2bf(a4) | ((unsigned)f2bf(a5) << 16);
    p.w = f2bf(a6) | ((unsigned)f2bf(a7) << 16);
    apre[r * 64 + l] = p;
}

// ---------------- kernel 2: barrier-free streaming MFMA sim + per-wave top-4 ----------------
// Queries (B operand) in LDS [c:16][q:128][64B], swizzle XOR bits 4-5 only (bijective
// within each 64B row). Each wave streams 16-img-row tiles (grid-stride), A-frags
// direct from global, 4-chunk register prefetch, zero barriers in the hot loop.
// launch_bounds(512,1): 1 block/CU -> 256-VGPR budget; persistent state (~170 VGPR)
// fits without spill. (R5: (512,2) capped VGPR at 128 -> 456 MB scratch traffic.)
__global__ __launch_bounds__(512, 1)
void sim_topk(const uint4* __restrict__ apre, const float* __restrict__ img,
              int N, int ntiles, float* __restrict__ pv, int* __restrict__ pi)
{
    extern __shared__ __align__(16) unsigned char Bs[];   // 131072 B
    const int tid  = threadIdx.x;
    const int lane = tid & 63;
    const int wid  = tid >> 6;
    const int lr   = lane & 15;
    const int kg   = lane >> 4;

    // stage query frags -> swizzled LDS (one-time)
    #pragma unroll
    for (int j = 0; j < 16; ++j) {
        int s = tid + j * 512;                 // 0..8191
        uint4 p = apre[s];
        int q = s >> 6, c = (s >> 2) & 15, g = s & 3;
        int addr = c * 8192 + q * 64 + ((g * 16) ^ ((q & 3) << 4));
        *(uint4*)(Bs + addr) = p;
    }
    __syncthreads();

    // frag(nf, c) = Bs + c*8192 + nf*1024 + lane_off
    const int lane_off = lr * 64 + ((kg * 16) ^ ((lr & 3) << 4));

    // per-lane running top-4 for 8 queries (q = nf*16 + lr)
    float lv[8][4]; int lc[8][4];
    #pragma unroll
    for (int nf = 0; nf < 8; ++nf)
        #pragma unroll
        for (int s = 0; s < 4; ++s) { lv[nf][s] = -1e30f; lc[nf][s] = SENT; }

    const int gwave = blockIdx.x * WPB + wid;
    int t = gwave;
    const float* gp;
    {
        int row = t * 16 + lr;
        if (row >= N) row = N - 1;
        gp = img + (size_t)row * D + kg * 8;
    }

    float4 pre[4][2];
    if (t < ntiles) {
        #pragma unroll
        for (int c = 0; c < 4; ++c) {
            pre[c][0] = *(const float4*)(gp + c * 32);
            pre[c][1] = *(const float4*)(gp + c * 32 + 4);
        }
    }

#define CHUNK(c) do {                                                          \
        float4 f0_ = pre[(c) & 3][0], f1_ = pre[(c) & 3][1];                   \
        if ((c) < 12) {                                                        \
            pre[(c) & 3][0] = *(const float4*)(gp + ((c) + 4) * 32);           \
            pre[(c) & 3][1] = *(const float4*)(gp + ((c) + 4) * 32 + 4);       \
        } else {                                                               \
            pre[(c) & 3][0] = *(const float4*)(gpn + ((c) - 12) * 32);         \
            pre[(c) & 3][1] = *(const float4*)(gpn + ((c) - 12) * 32 + 4);     \
        }                                                                      \
        sq += f0_.x*f0_.x + f0_.y*f0_.y + f0_.z*f0_.z + f0_.w*f0_.w            \
            + f1_.x*f1_.x + f1_.y*f1_.y + f1_.z*f1_.z + f1_.w*f1_.w;           \
        bf16x8 a_ = cvt8(f0_, f1_);                                            \
        const unsigned char* bp_ = Bs + (c) * 8192 + lane_off;                 \
        _Pragma("unroll")                                                      \
        for (int nf_ = 0; nf_ < 8; ++nf_) {                                    \
            bf16x8 b_ = *(const bf16x8*)(bp_ + nf_ * 1024);                    \
            acc[nf_] = __builtin_amdgcn_mfma_f32_16x16x32_bf16(a_, b_, acc[nf_], 0, 0, 0); \
        }                                                                      \
    } while (0)

    while (t < ntiles) {
        int tn = t + NWAVES;
        const float* gpn;
        {
            int tt = (tn < ntiles) ? tn : t;
            int row = tt * 16 + lr;
            if (row >= N) row = N - 1;
            gpn = img + (size_t)row * D + kg * 8;
        }
        f32x4 acc[8];
        #pragma unroll
        for (int nf = 0; nf < 8; ++nf) acc[nf] = (f32x4){0.f, 0.f, 0.f, 0.f};
        float sq = 0.f;

        CHUNK(0);  CHUNK(1);  CHUNK(2);  CHUNK(3);
        CHUNK(4);  CHUNK(5);  CHUNK(6);  CHUNK(7);
        CHUNK(8);  CHUNK(9);  CHUNK(10); CHUNK(11);
        CHUNK(12); CHUNK(13); CHUNK(14); CHUNK(15);

        // row norms: lane's sq covers its row's kg-slices; butterfly over kg lanes
        float s2 = sq;
        s2 += __shfl_xor(s2, 16);
        s2 += __shfl_xor(s2, 32);
        float rnorm = s2 > 0.f ? rsqrtf(s2) : 0.f;
        float rn[4];
        #pragma unroll
        for (int g = 0; g < 4; ++g) rn[g] = __shfl(rnorm, kg * 4 + g);

        const int ib = t * 16 + kg * 4;
        #pragma unroll
        for (int nf = 0; nf < 8; ++nf) {
            #pragma unroll
            for (int g = 0; g < 4; ++g) {
                int idx = ib + g;
                if (idx < N) ins4a(acc[nf][g] * rn[g], idx, lv[nf], lc[nf]);
            }
        }
        t = tn; gp = gpn;
    }
#undef CHUNK

    // merge across the 4 kg lane-groups (same query lives in lanes lr, lr+16, lr+32, lr+48)
    #pragma unroll
    for (int nf = 0; nf < 8; ++nf) {
        #pragma unroll
        for (int st = 0; st < 2; ++st) {
            const int off = st ? 32 : 16;
            float mv[4]; int mc[4];
            #pragma unroll
            for (int s = 0; s < 4; ++s) {
                mv[s] = __shfl_xor(lv[nf][s], off);
                mc[s] = __shfl_xor(lc[nf][s], off);
            }
            #pragma unroll
            for (int s = 0; s < 4; ++s) ins4a(mv[s], mc[s], lv[nf], lc[nf]);
        }
    }

    // block-level merge in LDS (query buffer dead now)
    __syncthreads();
    if (kg == 0) {
        #pragma unroll
        for (int nf = 0; nf < 8; ++nf) {
            int q = nf * 16 + lr;
            float* mv = (float*)(Bs + ((size_t)wid * 128 + q) * 32);
            int*   mi = (int*)(mv + 4);
            #pragma unroll
            for (int s = 0; s < 4; ++s) { mv[s] = lv[nf][s]; mi[s] = lc[nf][s]; }
        }
    }
    __syncthreads();
    if (tid < BQ) {
        int q = tid;
        float V[4]; int C[4];
        #pragma unroll
        for (int s = 0; s < 4; ++s) { V[s] = -1e30f; C[s] = SENT; }
        for (int w = 0; w < WPB; ++w) {
            const float* mv = (const float*)(Bs + ((size_t)w * 128 + q) * 32);
            const int*   mi = (const int*)(mv + 4);
            #pragma unroll
            for (int s = 0; s < 4; ++s)
                if (mi[s] != SENT) ins4a(mv[s], mi[s], V, C);
        }
        size_t base = (size_t)q * NB4 + (size_t)blockIdx.x * 4;
        #pragma unroll
        for (int s = 0; s < 4; ++s) { pv[base + s] = V[s]; pi[base + s] = C[s]; }
    }
}

// ---------------- kernel 3: reduce partials -> top-8 -> exact rescore -> weights ----
__global__ __launch_bounds__(256)
void reduce_rescore(const float* __restrict__ pv, const int* __restrict__ pi, int nb4,
                    const float* __restrict__ ihat, const float* __restrict__ img,
                    float* __restrict__ swo, int* __restrict__ sidxo,
                    int* __restrict__ valido)
{
    __shared__ float lv[256][8];
    __shared__ int   li[256][8];
    __shared__ float sv[8];
    __shared__ int   si[8];
    const int r = blockIdx.x, tid = threadIdx.x;

    float V[8]; int C[8];
    #pragma unroll
    for (int k = 0; k < 8; ++k) { V[k] = -1e30f; C[k] = SENT; }
    const float* prow = pv + (size_t)r * nb4;
    const int*   irow = pi + (size_t)r * nb4;
    for (int j = tid; j < nb4; j += 256) {
        int c = irow[j];
        if (c != SENT) insK<8>(prow[j], c, V, C);
    }
    #pragma unroll
    for (int k = 0; k < 8; ++k) { lv[tid][k] = V[k]; li[tid][k] = C[k]; }
    __syncthreads();
    if (tid < 16) {
        for (int o = 1; o < 16; ++o) {
            int t2 = tid + o * 16;
            #pragma unroll
            for (int s = 0; s < 8; ++s)
                if (li[t2][s] != SENT) insK<8>(lv[t2][s], li[t2][s], V, C);
        }
        #pragma unroll
        for (int k = 0; k < 8; ++k) { lv[tid][k] = V[k]; li[tid][k] = C[k]; }
    }
    __syncthreads();
    if (tid == 0) {
        for (int o = 1; o < 16; ++o)
            #pragma unroll
            for (int s = 0; s < 8; ++s)
                if (li[o][s] != SENT) insK<8>(lv[o][s], li[o][s], V, C);
        #pragma unroll
        for (int k = 0; k < 8; ++k) si[k] = C[k];
    }
    __syncthreads();

    // exact fp32 rescore of the 8 candidates (32 lanes each)
    {
        const int k = tid >> 5, l = tid & 31;
        int idx = si[k];
        float dot = 0.f, ssq = 0.f;
        if (idx != SENT) {
            const float* a = ihat + (size_t)r * D + l * 16;
            const float* b = img + (size_t)idx * D + l * 16;
            #pragma unroll
            for (int j = 0; j < 4; ++j) {
                float4 va = *(const float4*)(a + j*4);
                float4 vb = *(const float4*)(b + j*4);
                dot += va.x*vb.x + va.y*vb.y + va.z*vb.z + va.w*vb.w;
                ssq += vb.x*vb.x + vb.y*vb.y + vb.z*vb.z + vb.w*vb.w;
            }
        }
        #pragma unroll
        for (int o = 16; o > 0; o >>= 1) { dot += __shfl_xor(dot, o); ssq += __shfl_xor(ssq, o); }
        if (l == 0) sv[k] = (idx != SENT && ssq > 0.f) ? dot * rsqrtf(ssq) : -1e30f;
    }
    __syncthreads();

    if (tid == 0) {
        float Vt[4]; int Ct[4];
        #pragma unroll
        for (int k = 0; k < 4; ++k) { Vt[k] = -1e30f; Ct[k] = SENT; }
        #pragma unroll
        for (int k = 0; k < 8; ++k)
            if (si[k] != SENT) insK<4>(sv[k], si[k], Vt, Ct);
        float lg[4]; int vd[3];
        lg[0] = SSCALE;
        #pragma unroll
        for (int k = 0; k < 3; ++k) {
            vd[k] = (Vt[k+1] > THR) ? 1 : 0;
            lg[k+1] = vd[k] ? SSCALE * Vt[k+1] : -1e30f;
        }
        float m = fmaxf(fmaxf(lg[0], lg[1]), fmaxf(lg[2], lg[3]));
        float e0 = expf(lg[0]-m), e1 = expf(lg[1]-m), e2 = expf(lg[2]-m), e3 = expf(lg[3]-m);
        float sum = e0 + e1 + e2 + e3;
        float ee[3] = {e1, e2, e3};
        #pragma unroll
        for (int k = 0; k < 3; ++k) {
            float w = 1.0f - ee[k] / sum;
            swo[r*3+k]    = vd[k] ? w : 0.0f;
            sidxo[r*3+k]  = vd[k] ? Ct[k+1] : 0;
            valido[r*3+k] = vd[k];
        }
    }
}

// ---------------- kernel 4: assemble output (1536 x 512 fp32) ----------------
__global__ void assemble_kernel(const float* __restrict__ i_feats, const float* __restrict__ t_feats,
                                const float* __restrict__ img, const float* __restrict__ txt,
                                const float* __restrict__ sw, const int* __restrict__ sidx,
                                const int* __restrict__ valid, float* __restrict__ out)
{
    const int r = blockIdx.x;      // 0..1535
    const int t = threadIdx.x;     // 0..127
    float4* orow = (float4*)(out + (size_t)r * D);
    if (r < 128) {
        orow[t] = ((const float4*)(i_feats + (size_t)r * D))[t];
    } else if (r < 512) {
        int s = r - 128;
        float4 v = make_float4(0.f,0.f,0.f,0.f);
        if (valid[s]) v = ((const float4*)(img + (size_t)sidx[s] * D))[t];
        orow[t] = v;
    } else if (r < 640) {
        orow[t] = ((const float4*)(t_feats + (size_t)(r - 512) * D))[t];
    } else if (r < 1024) {
        int s = r - 640;
        float4 v = make_float4(0.f,0.f,0.f,0.f);
        if (valid[s]) v = ((const float4*)(txt + (size_t)sidx[s] * D))[t];
        orow[t] = v;
    } else {
        int li = r - 1024;
        float o[4];
        int j0 = t * 4;
        if (li < 128) {
            #pragma unroll
            for (int u = 0; u < 4; ++u) {
                int j = j0 + u;
                if (j < 128) o[u] = (j == li) ? 1.0f : 0.0f;
                else {
                    int s = j - 128;
                    o[u] = (s / 3 == li) ? sw[li*3 + (s % 3)] : 0.0f;
                }
            }
        } else {
            int i2 = li - 128;
            int b = i2 / 3;
            int vi = valid[i2];
            #pragma unroll
            for (int u = 0; u < 4; ++u) {
                int j = j0 + u;
                float val;
                if (j < 128) val = (vi && j == b) ? 1.0f : 0.0f;
                else {
                    int s2 = j - 128;
                    int vj = valid[s2];
                    int b2 = s2 / 3;
                    if (vi && vj)        val = (b == b2) ? 1.0f : 0.0f;
                    else if (!vi && !vj) val = (i2 == s2) ? 1.0f : 0.0f;
                    else                 val = 0.0f;
                }
                o[u] = val;
            }
        }
        orow[t] = make_float4(o[0], o[1], o[2], o[3]);
    }
}

extern "C" void kernel_launch(void* const* d_in, const int* in_sizes, int n_in,
                              void* d_out, int out_size, void* d_ws, size_t ws_size,
                              hipStream_t stream) {
    const float* i_feats = (const float*)d_in[0];
    const float* t_feats = (const float*)d_in[1];
    const float* img     = (const float*)d_in[2];
    const float* txt     = (const float*)d_in[3];
    float* out = (float*)d_out;

    const int N      = in_sizes[2] / D;        // 200000
    const int ntiles = (N + 15) / 16;          // 12500

    char* ws = (char*)d_ws;
    size_t off = 0;
    float* ihat = (float*)(ws + off); off += (size_t)BQ * D * 4;          // 256 KB
    uint4* apre = (uint4*)(ws + off); off += (size_t)BQ * D * 2;          // 128 KB
    float* pv   = (float*)(ws + off); off += (size_t)BQ * NB4 * 4;        // 512 KB
    int*   pi   = (int*)(ws + off);   off += (size_t)BQ * NB4 * 4;        // 512 KB
    float* swv  = (float*)(ws + off); off += BQ * 4 * 4;
    int*   sidx = (int*)(ws + off);   off += BQ * 4 * 4;
    int*   vld  = (int*)(ws + off);   off += BQ * 4 * 4;

    prep_kernel<<<BQ, 64, 0, stream>>>(i_feats, ihat, apre);
    sim_topk<<<NBLK, 512, 131072, stream>>>(apre, img, N, ntiles, pv, pi);
    reduce_rescore<<<BQ, 256, 0, stream>>>(pv, pi, NB4, ihat, img, swv, sidx, vld);
    assemble_kernel<<<3 * (BQ + BQ * KK), 128, 0, stream>>>(i_feats, t_feats, img, txt,
                                                            swv, sidx, vld, out);
}

// Round 7
// 707.424 us; speedup vs baseline: 1.4764x; 1.0049x over previous
//
#include <hip/hip_runtime.h>
#include <hip/hip_bf16.h>
#include <math.h>

#define D      512
#define BQ     128
#define KK     3
#define THR    0.15f
#define SSCALE 5.0f
#define SENT   0x7fffffff
#define NBLK   256
#define WPB    8
#define NWAVES (NBLK * WPB)
#define NB4    (NBLK * 4)

using bf16x8 = __attribute__((ext_vector_type(8))) short;
using f32x4  = __attribute__((ext_vector_type(4))) float;

__device__ __forceinline__ unsigned short f2bf(float x) {
    unsigned u = __float_as_uint(x);
    return (unsigned short)((u + 0x7fffu + ((u >> 16) & 1u)) >> 16);
}

__device__ __forceinline__ unsigned pk2(float lo, float hi) {
    __hip_bfloat162 h = __float22bfloat162_rn(make_float2(lo, hi));
    union { __hip_bfloat162 h; unsigned u; } c; c.h = h;
    return c.u;
}

__device__ __forceinline__ bf16x8 cvt8(float4 f0, float4 f1) {
    union { unsigned u[4]; bf16x8 v; } r;
    r.u[0] = pk2(f0.x, f0.y);
    r.u[1] = pk2(f0.z, f0.w);
    r.u[2] = pk2(f1.x, f1.y);
    r.u[3] = pk2(f1.z, f1.w);
    return r.v;
}

// tie-aware top-4 insert (descending, lower index wins ties) — matches jax.lax.top_k
__device__ __forceinline__ void ins4a(float v, int c, float V[4], int C[4]) {
    bool b0 = (v > V[0]) || (v == V[0] && c < C[0]);
    bool b1 = (v > V[1]) || (v == V[1] && c < C[1]);
    bool b2 = (v > V[2]) || (v == V[2] && c < C[2]);
    bool b3 = (v > V[3]) || (v == V[3] && c < C[3]);
    if (b0)      { V[3]=V[2]; C[3]=C[2]; V[2]=V[1]; C[2]=C[1]; V[1]=V[0]; C[1]=C[0]; V[0]=v; C[0]=c; }
    else if (b1) { V[3]=V[2]; C[3]=C[2]; V[2]=V[1]; C[2]=C[1]; V[1]=v;  C[1]=c; }
    else if (b2) { V[3]=V[2]; C[3]=C[2]; V[2]=v;  C[2]=c; }
    else if (b3) { V[3]=v;  C[3]=c; }
}

template<int K>
__device__ __forceinline__ void insK(float v, int c, float* V, int* C) {
    #pragma unroll
    for (int k = 0; k < K; ++k) {
        if (v > V[k] || (v == V[k] && c < C[k])) {
            #pragma unroll
            for (int m = K - 1; m > k; --m) { V[m] = V[m-1]; C[m] = C[m-1]; }
            V[k] = v; C[k] = c;
            return;
        }
    }
}

// ---------------- kernel 1: normalize i_feats + query bf16 fragment image ----------------
// apre slot = q*64 + c*4 + g (16B each): bf16 of ihat[q][k], k = c*32 + g*8 .. +8
__global__ void prep_kernel(const float* __restrict__ x, float* __restrict__ ihat,
                            uint4* __restrict__ apre) {
    int r = blockIdx.x;
    int l = threadIdx.x;             // 0..63, owns k = l*8 .. +8  (c = l>>2, g = l&3)
    const float4* row = (const float4*)(x + (size_t)r * D);
    float4 v0 = row[l * 2 + 0];
    float4 v1 = row[l * 2 + 1];
    float s = v0.x*v0.x + v0.y*v0.y + v0.z*v0.z + v0.w*v0.w
            + v1.x*v1.x + v1.y*v1.y + v1.z*v1.z + v1.w*v1.w;
    #pragma unroll
    for (int off = 32; off > 0; off >>= 1) s += __shfl_xor(s, off);
    float inv = 1.0f / sqrtf(s);
    float a0 = v0.x*inv, a1 = v0.y*inv, a2 = v0.z*inv, a3 = v0.w*inv;
    float a4 = v1.x*inv, a5 = v1.y*inv, a6 = v1.z*inv, a7 = v1.w*inv;
    float4* orow = (float4*)(ihat + (size_t)r * D);
    orow[l*2+0] = make_float4(a0, a1, a2, a3);
    orow[l*2+1] = make_float4(a4, a5, a6, a7);
    uint4 p;
    p.x = f2bf(a0) | ((unsigned)f2bf(a1) << 16);
    p.y = f2bf(a2) | ((unsigned)f2bf(a3) << 16);
    p.z = f2bf(a4) | ((unsigned)f2bf(a5) << 16);
    p.w = f2bf(a6) | ((unsigned)f2bf(a7) << 16);
    apre[r * 64 + l] = p;
}

// ---------------- kernel 2: barrier-free streaming MFMA sim + per-wave top-4 ----------------
// Queries (B operand) in LDS [c:16][q:128][64B], swizzle XOR bits 4-5 only (bijective
// within each 64B row). Each wave streams 16-img-row tiles (grid-stride), A-frags
// direct from global, 4-chunk register prefetch, zero barriers in the hot loop.
// amdgpu_waves_per_eu(2,2): LDS (128KB) already caps at 1 block/CU = 2 waves/EU, so
// pin min=max=2 -> register budget 512/2 = 256 VGPR/wave. (R5/R6: HIP __launch_bounds__
// only sets the MIN waves-per-eu; LLVM's allocator still targeted 4 waves/EU -> 128-reg
// cap -> per-tile spill/fill of the 64-reg top-k state = 445/222 MB scratch traffic.)
__global__ __launch_bounds__(512)
__attribute__((amdgpu_waves_per_eu(2, 2)))
void sim_topk(const uint4* __restrict__ apre, const float* __restrict__ img,
              int N, int ntiles, float* __restrict__ pv, int* __restrict__ pi)
{
    extern __shared__ __align__(16) unsigned char Bs[];   // 131072 B
    const int tid  = threadIdx.x;
    const int lane = tid & 63;
    const int wid  = tid >> 6;
    const int lr   = lane & 15;
    const int kg   = lane >> 4;

    // stage query frags -> swizzled LDS (one-time)
    #pragma unroll
    for (int j = 0; j < 16; ++j) {
        int s = tid + j * 512;                 // 0..8191
        uint4 p = apre[s];
        int q = s >> 6, c = (s >> 2) & 15, g = s & 3;
        int addr = c * 8192 + q * 64 + ((g * 16) ^ ((q & 3) << 4));
        *(uint4*)(Bs + addr) = p;
    }
    __syncthreads();

    // frag(nf, c) = Bs + c*8192 + nf*1024 + lane_off
    const int lane_off = lr * 64 + ((kg * 16) ^ ((lr & 3) << 4));

    // per-lane running top-4 for 8 queries (q = nf*16 + lr)
    float lv[8][4]; int lc[8][4];
    #pragma unroll
    for (int nf = 0; nf < 8; ++nf)
        #pragma unroll
        for (int s = 0; s < 4; ++s) { lv[nf][s] = -1e30f; lc[nf][s] = SENT; }

    const int gwave = blockIdx.x * WPB + wid;
    int t = gwave;
    const float* gp;
    {
        int row = t * 16 + lr;
        if (row >= N) row = N - 1;
        gp = img + (size_t)row * D + kg * 8;
    }

    float4 pre[4][2];
    if (t < ntiles) {
        #pragma unroll
        for (int c = 0; c < 4; ++c) {
            pre[c][0] = *(const float4*)(gp + c * 32);
            pre[c][1] = *(const float4*)(gp + c * 32 + 4);
        }
    }

#define CHUNK(c) do {                                                          \
        float4 f0_ = pre[(c) & 3][0], f1_ = pre[(c) & 3][1];                   \
        if ((c) < 12) {                                                        \
            pre[(c) & 3][0] = *(const float4*)(gp + ((c) + 4) * 32);           \
            pre[(c) & 3][1] = *(const float4*)(gp + ((c) + 4) * 32 + 4);       \
        } else {                                                               \
            pre[(c) & 3][0] = *(const float4*)(gpn + ((c) - 12) * 32);         \
            pre[(c) & 3][1] = *(const float4*)(gpn + ((c) - 12) * 32 + 4);     \
        }                                                                      \
        sq += f0_.x*f0_.x + f0_.y*f0_.y + f0_.z*f0_.z + f0_.w*f0_.w            \
            + f1_.x*f1_.x + f1_.y*f1_.y + f1_.z*f1_.z + f1_.w*f1_.w;           \
        bf16x8 a_ = cvt8(f0_, f1_);                                            \
        const unsigned char* bp_ = Bs + (c) * 8192 + lane_off;                 \
        _Pragma("unroll")                                                      \
        for (int nf_ = 0; nf_ < 8; ++nf_) {                                    \
            bf16x8 b_ = *(const bf16x8*)(bp_ + nf_ * 1024);                    \
            acc[nf_] = __builtin_amdgcn_mfma_f32_16x16x32_bf16(a_, b_, acc[nf_], 0, 0, 0); \
        }                                                                      \
    } while (0)

    while (t < ntiles) {
        int tn = t + NWAVES;
        const float* gpn;
        {
            int tt = (tn < ntiles) ? tn : t;
            int row = tt * 16 + lr;
            if (row >= N) row = N - 1;
            gpn = img + (size_t)row * D + kg * 8;
        }
        f32x4 acc[8];
        #pragma unroll
        for (int nf = 0; nf < 8; ++nf) acc[nf] = (f32x4){0.f, 0.f, 0.f, 0.f};
        float sq = 0.f;

        CHUNK(0);  CHUNK(1);  CHUNK(2);  CHUNK(3);
        CHUNK(4);  CHUNK(5);  CHUNK(6);  CHUNK(7);
        CHUNK(8);  CHUNK(9);  CHUNK(10); CHUNK(11);
        CHUNK(12); CHUNK(13); CHUNK(14); CHUNK(15);

        // row norms: lane's sq covers its row's kg-slices; butterfly over kg lanes
        float s2 = sq;
        s2 += __shfl_xor(s2, 16);
        s2 += __shfl_xor(s2, 32);
        float rnorm = s2 > 0.f ? rsqrtf(s2) : 0.f;
        float rn[4];
        #pragma unroll
        for (int g = 0; g < 4; ++g) rn[g] = __shfl(rnorm, kg * 4 + g);

        const int ib = t * 16 + kg * 4;
        #pragma unroll
        for (int nf = 0; nf < 8; ++nf) {
            #pragma unroll
            for (int g = 0; g < 4; ++g) {
                int idx = ib + g;
                if (idx < N) ins4a(acc[nf][g] * rn[g], idx, lv[nf], lc[nf]);
            }
        }
        t = tn; gp = gpn;
    }
#undef CHUNK

    // merge across the 4 kg lane-groups (same query lives in lanes lr, lr+16, lr+32, lr+48)
    #pragma unroll
    for (int nf = 0; nf < 8; ++nf) {
        #pragma unroll
        for (int st = 0; st < 2; ++st) {
            const int off = st ? 32 : 16;
            float mv[4]; int mc[4];
            #pragma unroll
            for (int s = 0; s < 4; ++s) {
                mv[s] = __shfl_xor(lv[nf][s], off);
                mc[s] = __shfl_xor(lc[nf][s], off);
            }
            #pragma unroll
            for (int s = 0; s < 4; ++s) ins4a(mv[s], mc[s], lv[nf], lc[nf]);
        }
    }

    // block-level merge in LDS (query buffer dead now)
    __syncthreads();
    if (kg == 0) {
        #pragma unroll
        for (int nf = 0; nf < 8; ++nf) {
            int q = nf * 16 + lr;
            float* mv = (float*)(Bs + ((size_t)wid * 128 + q) * 32);
            int*   mi = (int*)(mv + 4);
            #pragma unroll
            for (int s = 0; s < 4; ++s) { mv[s] = lv[nf][s]; mi[s] = lc[nf][s]; }
        }
    }
    __syncthreads();
    if (tid < BQ) {
        int q = tid;
        float V[4]; int C[4];
        #pragma unroll
        for (int s = 0; s < 4; ++s) { V[s] = -1e30f; C[s] = SENT; }
        for (int w = 0; w < WPB; ++w) {
            const float* mv = (const float*)(Bs + ((size_t)w * 128 + q) * 32);
            const int*   mi = (const int*)(mv + 4);
            #pragma unroll
            for (int s = 0; s < 4; ++s)
                if (mi[s] != SENT) ins4a(mv[s], mi[s], V, C);
        }
        size_t base = (size_t)q * NB4 + (size_t)blockIdx.x * 4;
        #pragma unroll
        for (int s = 0; s < 4; ++s) { pv[base + s] = V[s]; pi[base + s] = C[s]; }
    }
}

// ---------------- kernel 3: reduce partials -> top-8 -> exact rescore -> weights ----
__global__ __launch_bounds__(256)
void reduce_rescore(const float* __restrict__ pv, const int* __restrict__ pi, int nb4,
                    const float* __restrict__ ihat, const float* __restrict__ img,
                    float* __restrict__ swo, int* __restrict__ sidxo,
                    int* __restrict__ valido)
{
    __shared__ float lv[256][8];
    __shared__ int   li[256][8];
    __shared__ float sv[8];
    __shared__ int   si[8];
    const int r = blockIdx.x, tid = threadIdx.x;

    float V[8]; int C[8];
    #pragma unroll
    for (int k = 0; k < 8; ++k) { V[k] = -1e30f; C[k] = SENT; }
    const float* prow = pv + (size_t)r * nb4;
    const int*   irow = pi + (size_t)r * nb4;
    for (int j = tid; j < nb4; j += 256) {
        int c = irow[j];
        if (c != SENT) insK<8>(prow[j], c, V, C);
    }
    #pragma unroll
    for (int k = 0; k < 8; ++k) { lv[tid][k] = V[k]; li[tid][k] = C[k]; }
    __syncthreads();
    if (tid < 16) {
        for (int o = 1; o < 16; ++o) {
            int t2 = tid + o * 16;
            #pragma unroll
            for (int s = 0; s < 8; ++s)
                if (li[t2][s] != SENT) insK<8>(lv[t2][s], li[t2][s], V, C);
        }
        #pragma unroll
        for (int k = 0; k < 8; ++k) { lv[tid][k] = V[k]; li[tid][k] = C[k]; }
    }
    __syncthreads();
    if (tid == 0) {
        for (int o = 1; o < 16; ++o)
            #pragma unroll
            for (int s = 0; s < 8; ++s)
                if (li[o][s] != SENT) insK<8>(lv[o][s], li[o][s], V, C);
        #pragma unroll
        for (int k = 0; k < 8; ++k) si[k] = C[k];
    }
    __syncthreads();

    // exact fp32 rescore of the 8 candidates (32 lanes each)
    {
        const int k = tid >> 5, l = tid & 31;
        int idx = si[k];
        float dot = 0.f, ssq = 0.f;
        if (idx != SENT) {
            const float* a = ihat + (size_t)r * D + l * 16;
            const float* b = img + (size_t)idx * D + l * 16;
            #pragma unroll
            for (int j = 0; j < 4; ++j) {
                float4 va = *(const float4*)(a + j*4);
                float4 vb = *(const float4*)(b + j*4);
                dot += va.x*vb.x + va.y*vb.y + va.z*vb.z + va.w*vb.w;
                ssq += vb.x*vb.x + vb.y*vb.y + vb.z*vb.z + vb.w*vb.w;
            }
        }
        #pragma unroll
        for (int o = 16; o > 0; o >>= 1) { dot += __shfl_xor(dot, o); ssq += __shfl_xor(ssq, o); }
        if (l == 0) sv[k] = (idx != SENT && ssq > 0.f) ? dot * rsqrtf(ssq) : -1e30f;
    }
    __syncthreads();

    if (tid == 0) {
        float Vt[4]; int Ct[4];
        #pragma unroll
        for (int k = 0; k < 4; ++k) { Vt[k] = -1e30f; Ct[k] = SENT; }
        #pragma unroll
        for (int k = 0; k < 8; ++k)
            if (si[k] != SENT) insK<4>(sv[k], si[k], Vt, Ct);
        float lg[4]; int vd[3];
        lg[0] = SSCALE;
        #pragma unroll
        for (int k = 0; k < 3; ++k) {
            vd[k] = (Vt[k+1] > THR) ? 1 : 0;
            lg[k+1] = vd[k] ? SSCALE * Vt[k+1] : -1e30f;
        }
        float m = fmaxf(fmaxf(lg[0], lg[1]), fmaxf(lg[2], lg[3]));
        float e0 = expf(lg[0]-m), e1 = expf(lg[1]-m), e2 = expf(lg[2]-m), e3 = expf(lg[3]-m);
        float sum = e0 + e1 + e2 + e3;
        float ee[3] = {e1, e2, e3};
        #pragma unroll
        for (int k = 0; k < 3; ++k) {
            float w = 1.0f - ee[k] / sum;
            swo[r*3+k]    = vd[k] ? w : 0.0f;
            sidxo[r*3+k]  = vd[k] ? Ct[k+1] : 0;
            valido[r*3+k] = vd[k];
        }
    }
}

// ---------------- kernel 4: assemble output (1536 x 512 fp32) ----------------
__global__ void assemble_kernel(const float* __restrict__ i_feats, const float* __restrict__ t_feats,
                                const float* __restrict__ img, const float* __restrict__ txt,
                                const float* __restrict__ sw, const int* __restrict__ sidx,
                                const int* __restrict__ valid, float* __restrict__ out)
{
    const int r = blockIdx.x;      // 0..1535
    const int t = threadIdx.x;     // 0..127
    float4* orow = (float4*)(out + (size_t)r * D);
    if (r < 128) {
        orow[t] = ((const float4*)(i_feats + (size_t)r * D))[t];
    } else if (r < 512) {
        int s = r - 128;
        float4 v = make_float4(0.f,0.f,0.f,0.f);
        if (valid[s]) v = ((const float4*)(img + (size_t)sidx[s] * D))[t];
        orow[t] = v;
    } else if (r < 640) {
        orow[t] = ((const float4*)(t_feats + (size_t)(r - 512) * D))[t];
    } else if (r < 1024) {
        int s = r - 640;
        float4 v = make_float4(0.f,0.f,0.f,0.f);
        if (valid[s]) v = ((const float4*)(txt + (size_t)sidx[s] * D))[t];
        orow[t] = v;
    } else {
        int li = r - 1024;
        float o[4];
        int j0 = t * 4;
        if (li < 128) {
            #pragma unroll
            for (int u = 0; u < 4; ++u) {
                int j = j0 + u;
                if (j < 128) o[u] = (j == li) ? 1.0f : 0.0f;
                else {
                    int s = j - 128;
                    o[u] = (s / 3 == li) ? sw[li*3 + (s % 3)] : 0.0f;
                }
            }
        } else {
            int i2 = li - 128;
            int b = i2 / 3;
            int vi = valid[i2];
            #pragma unroll
            for (int u = 0; u < 4; ++u) {
                int j = j0 + u;
                float val;
                if (j < 128) val = (vi && j == b) ? 1.0f : 0.0f;
                else {
                    int s2 = j - 128;
                    int vj = valid[s2];
                    int b2 = s2 / 3;
                    if (vi && vj)        val = (b == b2) ? 1.0f : 0.0f;
                    else if (!vi && !vj) val = (i2 == s2) ? 1.0f : 0.0f;
                    else                 val = 0.0f;
                }
                o[u] = val;
            }
        }
        orow[t] = make_float4(o[0], o[1], o[2], o[3]);
    }
}

extern "C" void kernel_launch(void* const* d_in, const int* in_sizes, int n_in,
                              void* d_out, int out_size, void* d_ws, size_t ws_size,
                              hipStream_t stream) {
    const float* i_feats = (const float*)d_in[0];
    const float* t_feats = (const float*)d_in[1];
    const float* img     = (const float*)d_in[2];
    const float* txt     = (const float*)d_in[3];
    float* out = (float*)d_out;

    const int N      = in_sizes[2] / D;        // 200000
    const int ntiles = (N + 15) / 16;          // 12500

    char* ws = (char*)d_ws;
    size_t off = 0;
    float* ihat = (float*)(ws + off); off += (size_t)BQ * D * 4;          // 256 KB
    uint4* apre = (uint4*)(ws + off); off += (size_t)BQ * D * 2;          // 128 KB
    float* pv   = (float*)(ws + off); off += (size_t)BQ * NB4 * 4;        // 512 KB
    int*   pi   = (int*)(ws + off);   off += (size_t)BQ * NB4 * 4;        // 512 KB
    float* swv  = (float*)(ws + off); off += BQ * 4 * 4;
    int*   sidx = (int*)(ws + off);   off += BQ * 4 * 4;
    int*   vld  = (int*)(ws + off);   off += BQ * 4 * 4;

    prep_kernel<<<BQ, 64, 0, stream>>>(i_feats, ihat, apre);
    sim_topk<<<NBLK, 512, 131072, stream>>>(apre, img, N, ntiles, pv, pi);
    reduce_rescore<<<BQ, 256, 0, stream>>>(pv, pi, NB4, ihat, img, swv, sidx, vld);
    assemble_kernel<<<3 * (BQ + BQ * KK), 128, 0, stream>>>(i_feats, t_feats, img, txt,
                                                            swv, sidx, vld, out);
}

// Round 8
// 536.694 us; speedup vs baseline: 1.9461x; 1.3181x over previous
//
#include <hip/hip_runtime.h>
#include <hip/hip_bf16.h>
#include <math.h>

#define D      512
#define BQ     128
#define KK     3
#define THR    0.15f
#define SSCALE 5.0f
#define SENT   0x7fffffff
#define NBLK   256
#define WPB    8
#define NWAVES (NBLK * WPB)
#define NB4    (NBLK * 4)
#define IDXM   0x3FFFFu

using bf16x8 = __attribute__((ext_vector_type(8))) short;
using f32x4  = __attribute__((ext_vector_type(4))) float;

__device__ __forceinline__ unsigned short f2bf(float x) {
    unsigned u = __float_as_uint(x);
    return (unsigned short)((u + 0x7fffu + ((u >> 16) & 1u)) >> 16);
}

__device__ __forceinline__ unsigned pk2(float lo, float hi) {
    __hip_bfloat162 h = __float22bfloat162_rn(make_float2(lo, hi));
    union { __hip_bfloat162 h; unsigned u; } c; c.h = h;
    return c.u;
}

__device__ __forceinline__ bf16x8 cvt8(float4 f0, float4 f1) {
    union { unsigned u[4]; bf16x8 v; } r;
    r.u[0] = pk2(f0.x, f0.y);
    r.u[1] = pk2(f0.z, f0.w);
    r.u[2] = pk2(f1.x, f1.y);
    r.u[3] = pk2(f1.z, f1.w);
    return r.v;
}

// ordered-float: monotone u32 mapping of f32
__device__ __forceinline__ unsigned ordf(float v) {
    unsigned u = __float_as_uint(v);
    return u ^ ((unsigned)((int)u >> 31) | 0x80000000u);
}

// guarded descending insert into a 4-key list (keys pack value|~idx: tie -> lower idx wins)
__device__ __forceinline__ void insk4(unsigned key, unsigned K[4]) {
    if (key > K[3]) {
        bool b0 = key > K[0], b1 = key > K[1], b2 = key > K[2];
        unsigned k0 = K[0], k1 = K[1], k2 = K[2];
        K[0] = b0 ? key : k0;
        K[1] = b0 ? k0 : (b1 ? key : k1);
        K[2] = b1 ? k1 : (b2 ? key : k2);
        K[3] = b2 ? k2 : key;
    }
}

__device__ __forceinline__ void insk8(unsigned key, unsigned* K) {
    if (key <= K[7]) return;
    #pragma unroll
    for (int k = 0; k < 8; ++k) {
        if (key > K[k]) {
            #pragma unroll
            for (int m = 7; m > k; --m) K[m] = K[m-1];
            K[k] = key;
            return;
        }
    }
}

// exact float top-4 with (value desc, idx asc) tie rule — matches jax.lax.top_k
template<int K>
__device__ __forceinline__ void insK(float v, int c, float* V, int* C) {
    #pragma unroll
    for (int k = 0; k < K; ++k) {
        if (v > V[k] || (v == V[k] && c < C[k])) {
            #pragma unroll
            for (int m = K - 1; m > k; --m) { V[m] = V[m-1]; C[m] = C[m-1]; }
            V[k] = v; C[k] = c;
            return;
        }
    }
}

// ---------------- kernel 1: normalize i_feats + query bf16 fragment image ----------------
// apre element (q, c, g) at index g*2048 + c*128 + q  (16B each): bf16 of
// ihat[q][k], k = c*32 + g*8 .. +8
__global__ void prep_kernel(const float* __restrict__ x, float* __restrict__ ihat,
                            uint4* __restrict__ apre) {
    int r = blockIdx.x;
    int l = threadIdx.x;             // 0..63, owns k = l*8 .. +8  (c = l>>2, g = l&3)
    const float4* row = (const float4*)(x + (size_t)r * D);
    float4 v0 = row[l * 2 + 0];
    float4 v1 = row[l * 2 + 1];
    float s = v0.x*v0.x + v0.y*v0.y + v0.z*v0.z + v0.w*v0.w
            + v1.x*v1.x + v1.y*v1.y + v1.z*v1.z + v1.w*v1.w;
    #pragma unroll
    for (int off = 32; off > 0; off >>= 1) s += __shfl_xor(s, off);
    float inv = 1.0f / sqrtf(s);
    float a0 = v0.x*inv, a1 = v0.y*inv, a2 = v0.z*inv, a3 = v0.w*inv;
    float a4 = v1.x*inv, a5 = v1.y*inv, a6 = v1.z*inv, a7 = v1.w*inv;
    float4* orow = (float4*)(ihat + (size_t)r * D);
    orow[l*2+0] = make_float4(a0, a1, a2, a3);
    orow[l*2+1] = make_float4(a4, a5, a6, a7);
    uint4 p;
    p.x = f2bf(a0) | ((unsigned)f2bf(a1) << 16);
    p.y = f2bf(a2) | ((unsigned)f2bf(a3) << 16);
    p.z = f2bf(a4) | ((unsigned)f2bf(a5) << 16);
    p.w = f2bf(a6) | ((unsigned)f2bf(a7) << 16);
    apre[((l & 3) << 11) + ((l >> 2) << 7) + r] = p;
}

// ---------------- kernel 2: barrier-free streaming MFMA sim + packed-key top-4 ----------------
// Query LDS layout: element (q,c,g) at c*8192 + g*2048 + q*16 — frag reads are 16
// consecutive lanes x 256B contiguous = bank-conflict-free (no XOR swizzle needed).
// Top-k state packed as u32 keys (value[14b] | idx^IDXM[18b]) -> 32 VGPR, so total
// demand ~116 fits the 128-VGPR budget (R5-R7: 64-reg fp32+idx state spilled 200+MB).
__global__ __launch_bounds__(512)
void sim_topk(const uint4* __restrict__ apre, const float* __restrict__ img,
              int N, int ntiles, unsigned* __restrict__ pk)
{
    extern __shared__ __align__(16) unsigned char Bs[];   // 131072 B
    const int tid  = threadIdx.x;
    const int lane = tid & 63;
    const int wid  = tid >> 6;
    const int lr   = lane & 15;
    const int kg   = lane >> 4;

    // stage query frags -> LDS (one-time): s = g*2048 + c*128 + q
    #pragma unroll
    for (int j = 0; j < 16; ++j) {
        int s = tid + j * 512;                 // 0..8191
        uint4 p = apre[s];
        int addr = ((s >> 7) & 15) * 8192 + (s >> 11) * 2048 + (s & 127) * 16;
        *(uint4*)(Bs + addr) = p;
    }
    __syncthreads();

    // frag(nf, c) = Bs + c*8192 + lane_off + nf*256
    const int lane_off = kg * 2048 + lr * 16;

    // per-lane running top-4 keys for 8 queries (q = nf*16 + lr)
    unsigned keys[8][4];
    #pragma unroll
    for (int nf = 0; nf < 8; ++nf)
        #pragma unroll
        for (int s = 0; s < 4; ++s) keys[nf][s] = 0u;

    const int gwave = blockIdx.x * WPB + wid;
    int t = gwave;
    const float* gp;
    {
        int row = t * 16 + lr;
        if (row >= N) row = N - 1;
        gp = img + (size_t)row * D + kg * 8;
    }

    float4 pre[4][2];
    if (t < ntiles) {
        #pragma unroll
        for (int c = 0; c < 4; ++c) {
            pre[c][0] = *(const float4*)(gp + c * 32);
            pre[c][1] = *(const float4*)(gp + c * 32 + 4);
        }
    }

#define CHUNK(c) do {                                                          \
        float4 f0_ = pre[(c) & 3][0], f1_ = pre[(c) & 3][1];                   \
        if ((c) < 12) {                                                        \
            pre[(c) & 3][0] = *(const float4*)(gp + ((c) + 4) * 32);           \
            pre[(c) & 3][1] = *(const float4*)(gp + ((c) + 4) * 32 + 4);       \
        } else {                                                               \
            pre[(c) & 3][0] = *(const float4*)(gpn + ((c) - 12) * 32);         \
            pre[(c) & 3][1] = *(const float4*)(gpn + ((c) - 12) * 32 + 4);     \
        }                                                                      \
        sq += f0_.x*f0_.x + f0_.y*f0_.y + f0_.z*f0_.z + f0_.w*f0_.w            \
            + f1_.x*f1_.x + f1_.y*f1_.y + f1_.z*f1_.z + f1_.w*f1_.w;           \
        bf16x8 a_ = cvt8(f0_, f1_);                                            \
        const unsigned char* bp_ = Bs + (c) * 8192 + lane_off;                 \
        _Pragma("unroll")                                                      \
        for (int nf_ = 0; nf_ < 8; ++nf_) {                                    \
            bf16x8 b_ = *(const bf16x8*)(bp_ + nf_ * 256);                     \
            acc[nf_] = __builtin_amdgcn_mfma_f32_16x16x32_bf16(a_, b_, acc[nf_], 0, 0, 0); \
        }                                                                      \
    } while (0)

    while (t < ntiles) {
        int tn = t + NWAVES;
        const float* gpn;
        {
            int tt = (tn < ntiles) ? tn : t;
            int row = tt * 16 + lr;
            if (row >= N) row = N - 1;
            gpn = img + (size_t)row * D + kg * 8;
        }
        f32x4 acc[8];
        #pragma unroll
        for (int nf = 0; nf < 8; ++nf) acc[nf] = (f32x4){0.f, 0.f, 0.f, 0.f};
        float sq = 0.f;

        CHUNK(0);  CHUNK(1);  CHUNK(2);  CHUNK(3);
        CHUNK(4);  CHUNK(5);  CHUNK(6);  CHUNK(7);
        CHUNK(8);  CHUNK(9);  CHUNK(10); CHUNK(11);
        CHUNK(12); CHUNK(13); CHUNK(14); CHUNK(15);

        // row norms: lane's sq covers its row's kg-slices; butterfly over kg lanes
        float s2 = sq;
        s2 += __shfl_xor(s2, 16);
        s2 += __shfl_xor(s2, 32);
        float rnorm = s2 > 0.f ? rsqrtf(s2) : 0.f;
        float rn[4];
        #pragma unroll
        for (int g = 0; g < 4; ++g) rn[g] = __shfl(rnorm, kg * 4 + g);

        const int ib = t * 16 + kg * 4;
        unsigned idxc[4]; bool okn[4];
        #pragma unroll
        for (int g = 0; g < 4; ++g) {
            int idx = ib + g;
            okn[g]  = idx < N;
            idxc[g] = (unsigned)idx ^ IDXM;
        }
        #pragma unroll
        for (int nf = 0; nf < 8; ++nf) {
            #pragma unroll
            for (int g = 0; g < 4; ++g) {
                unsigned o   = ordf(acc[nf][g] * rn[g]);
                unsigned key = (o & 0xFFFC0000u) | idxc[g];
                key = okn[g] ? key : 0u;
                insk4(key, keys[nf]);
            }
        }
        t = tn; gp = gpn;
    }
#undef CHUNK

    // merge across the 4 kg lane-groups (same query lives in lanes lr, lr+16, lr+32, lr+48)
    #pragma unroll
    for (int nf = 0; nf < 8; ++nf) {
        #pragma unroll
        for (int st = 0; st < 2; ++st) {
            const int off = st ? 32 : 16;
            unsigned mk[4];
            #pragma unroll
            for (int s = 0; s < 4; ++s) mk[s] = __shfl_xor((int)keys[nf][s], off);
            #pragma unroll
            for (int s = 0; s < 4; ++s) insk4(mk[s], keys[nf]);
        }
    }

    // block-level merge in LDS (query buffer dead now)
    __syncthreads();
    if (kg == 0) {
        #pragma unroll
        for (int nf = 0; nf < 8; ++nf) {
            int q = nf * 16 + lr;
            uint4 v;
            v.x = keys[nf][0]; v.y = keys[nf][1]; v.z = keys[nf][2]; v.w = keys[nf][3];
            *(uint4*)(Bs + ((size_t)wid * 128 + q) * 16) = v;
        }
    }
    __syncthreads();
    if (tid < BQ) {
        int q = tid;
        unsigned V[4] = {0u, 0u, 0u, 0u};
        #pragma unroll
        for (int w = 0; w < WPB; ++w) {
            uint4 kk = *(const uint4*)(Bs + ((size_t)w * 128 + q) * 16);
            insk4(kk.x, V); insk4(kk.y, V); insk4(kk.z, V); insk4(kk.w, V);
        }
        uint4 o; o.x = V[0]; o.y = V[1]; o.z = V[2]; o.w = V[3];
        *(uint4*)(pk + (size_t)q * NB4 + (size_t)blockIdx.x * 4) = o;
    }
}

// ---------------- kernel 3: reduce keys -> top-8 -> exact fp32 rescore -> weights ----
__global__ __launch_bounds__(256)
void reduce_rescore(const unsigned* __restrict__ pk, int nb4,
                    const float* __restrict__ ihat, const float* __restrict__ img, int N,
                    float* __restrict__ swo, int* __restrict__ sidxo,
                    int* __restrict__ valido)
{
    __shared__ unsigned lk[256][8];
    __shared__ float sv[8];
    __shared__ int   si[8];
    const int r = blockIdx.x, tid = threadIdx.x;

    unsigned K[8];
    #pragma unroll
    for (int k = 0; k < 8; ++k) K[k] = 0u;
    const unsigned* prow = pk + (size_t)r * nb4;
    for (int j = tid; j < nb4; j += 256) insk8(prow[j], K);
    #pragma unroll
    for (int k = 0; k < 8; ++k) lk[tid][k] = K[k];
    __syncthreads();
    if (tid < 16) {
        for (int o = 1; o < 16; ++o) {
            int t2 = tid + o * 16;
            #pragma unroll
            for (int s = 0; s < 8; ++s) insk8(lk[t2][s], K);
        }
        #pragma unroll
        for (int k = 0; k < 8; ++k) lk[tid][k] = K[k];
    }
    __syncthreads();
    if (tid == 0) {
        for (int o = 1; o < 16; ++o)
            #pragma unroll
            for (int s = 0; s < 8; ++s) insk8(lk[o][s], K);
        #pragma unroll
        for (int k = 0; k < 8; ++k) {
            int idx = (int)((K[k] & IDXM) ^ IDXM);
            si[k] = (K[k] != 0u && idx < N) ? idx : -1;
        }
    }
    __syncthreads();

    // exact fp32 rescore of the 8 candidates (32 lanes each)
    {
        const int k = tid >> 5, l = tid & 31;
        int idx = si[k];
        float dot = 0.f, ssq = 0.f;
        if (idx >= 0) {
            const float* a = ihat + (size_t)r * D + l * 16;
            const float* b = img + (size_t)idx * D + l * 16;
            #pragma unroll
            for (int j = 0; j < 4; ++j) {
                float4 va = *(const float4*)(a + j*4);
                float4 vb = *(const float4*)(b + j*4);
                dot += va.x*vb.x + va.y*vb.y + va.z*vb.z + va.w*vb.w;
                ssq += vb.x*vb.x + vb.y*vb.y + vb.z*vb.z + vb.w*vb.w;
            }
        }
        #pragma unroll
        for (int o = 16; o > 0; o >>= 1) { dot += __shfl_xor(dot, o); ssq += __shfl_xor(ssq, o); }
        if (l == 0) sv[k] = (idx >= 0 && ssq > 0.f) ? dot * rsqrtf(ssq) : -1e30f;
    }
    __syncthreads();

    if (tid == 0) {
        float Vt[4]; int Ct[4];
        #pragma unroll
        for (int k = 0; k < 4; ++k) { Vt[k] = -1e30f; Ct[k] = SENT; }
        #pragma unroll
        for (int k = 0; k < 8; ++k)
            if (si[k] >= 0) insK<4>(sv[k], si[k], Vt, Ct);
        float lg[4]; int vd[3];
        lg[0] = SSCALE;
        #pragma unroll
        for (int k = 0; k < 3; ++k) {
            vd[k] = (Vt[k+1] > THR) ? 1 : 0;
            lg[k+1] = vd[k] ? SSCALE * Vt[k+1] : -1e30f;
        }
        float m = fmaxf(fmaxf(lg[0], lg[1]), fmaxf(lg[2], lg[3]));
        float e0 = expf(lg[0]-m), e1 = expf(lg[1]-m), e2 = expf(lg[2]-m), e3 = expf(lg[3]-m);
        float sum = e0 + e1 + e2 + e3;
        float ee[3] = {e1, e2, e3};
        #pragma unroll
        for (int k = 0; k < 3; ++k) {
            float w = 1.0f - ee[k] / sum;
            swo[r*3+k]    = vd[k] ? w : 0.0f;
            sidxo[r*3+k]  = vd[k] ? Ct[k+1] : 0;
            valido[r*3+k] = vd[k];
        }
    }
}

// ---------------- kernel 4: assemble output (1536 x 512 fp32) ----------------
__global__ void assemble_kernel(const float* __restrict__ i_feats, const float* __restrict__ t_feats,
                                const float* __restrict__ img, const float* __restrict__ txt,
                                const float* __restrict__ sw, const int* __restrict__ sidx,
                                const int* __restrict__ valid, float* __restrict__ out)
{
    const int r = blockIdx.x;      // 0..1535
    const int t = threadIdx.x;     // 0..127
    float4* orow = (float4*)(out + (size_t)r * D);
    if (r < 128) {
        orow[t] = ((const float4*)(i_feats + (size_t)r * D))[t];
    } else if (r < 512) {
        int s = r - 128;
        float4 v = make_float4(0.f,0.f,0.f,0.f);
        if (valid[s]) v = ((const float4*)(img + (size_t)sidx[s] * D))[t];
        orow[t] = v;
    } else if (r < 640) {
        orow[t] = ((const float4*)(t_feats + (size_t)(r - 512) * D))[t];
    } else if (r < 1024) {
        int s = r - 640;
        float4 v = make_float4(0.f,0.f,0.f,0.f);
        if (valid[s]) v = ((const float4*)(txt + (size_t)sidx[s] * D))[t];
        orow[t] = v;
    } else {
        int li = r - 1024;
        float o[4];
        int j0 = t * 4;
        if (li < 128) {
            #pragma unroll
            for (int u = 0; u < 4; ++u) {
                int j = j0 + u;
                if (j < 128) o[u] = (j == li) ? 1.0f : 0.0f;
                else {
                    int s = j - 128;
                    o[u] = (s / 3 == li) ? sw[li*3 + (s % 3)] : 0.0f;
                }
            }
        } else {
            int i2 = li - 128;
            int b = i2 / 3;
            int vi = valid[i2];
            #pragma unroll
            for (int u = 0; u < 4; ++u) {
                int j = j0 + u;
                float val;
                if (j < 128) val = (vi && j == b) ? 1.0f : 0.0f;
                else {
                    int s2 = j - 128;
                    int vj = valid[s2];
                    int b2 = s2 / 3;
                    if (vi && vj)        val = (b == b2) ? 1.0f : 0.0f;
                    else if (!vi && !vj) val = (i2 == s2) ? 1.0f : 0.0f;
                    else                 val = 0.0f;
                }
                o[u] = val;
            }
        }
        orow[t] = make_float4(o[0], o[1], o[2], o[3]);
    }
}

extern "C" void kernel_launch(void* const* d_in, const int* in_sizes, int n_in,
                              void* d_out, int out_size, void* d_ws, size_t ws_size,
                              hipStream_t stream) {
    const float* i_feats = (const float*)d_in[0];
    const float* t_feats = (const float*)d_in[1];
    const float* img     = (const float*)d_in[2];
    const float* txt     = (const float*)d_in[3];
    float* out = (float*)d_out;

    const int N      = in_sizes[2] / D;        // 200000
    const int ntiles = (N + 15) / 16;          // 12500

    char* ws = (char*)d_ws;
    size_t off = 0;
    float*    ihat = (float*)(ws + off);    off += (size_t)BQ * D * 4;    // 256 KB
    uint4*    apre = (uint4*)(ws + off);    off += (size_t)BQ * D * 2;    // 128 KB
    unsigned* pk   = (unsigned*)(ws + off); off += (size_t)BQ * NB4 * 4;  // 512 KB
    float*    swv  = (float*)(ws + off);    off += BQ * 4 * 4;
    int*      sidx = (int*)(ws + off);      off += BQ * 4 * 4;
    int*      vld  = (int*)(ws + off);      off += BQ * 4 * 4;

    prep_kernel<<<BQ, 64, 0, stream>>>(i_feats, ihat, apre);
    sim_topk<<<NBLK, 512, 131072, stream>>>(apre, img, N, ntiles, pk);
    reduce_rescore<<<BQ, 256, 0, stream>>>(pk, NB4, ihat, img, N, swv, sidx, vld);
    assemble_kernel<<<3 * (BQ + BQ * KK), 128, 0, stream>>>(i_feats, t_feats, img, txt,
                                                            swv, sidx, vld, out);
}

// Round 9
// 206.352 us; speedup vs baseline: 5.0614x; 2.6009x over previous
//
#include <hip/hip_runtime.h>
#include <hip/hip_bf16.h>
#include <math.h>

#define D      512
#define BQ     128
#define KK     3
#define THR    0.15f
#define SSCALE 5.0f
#define SENT   0x7fffffff
#define NBLK   256
#define NSTR   (NBLK * 4)
#define NB4    (NBLK * 4)
#define IDXM   0x3FFFFu

using bf16x8 = __attribute__((ext_vector_type(8))) short;
using f32x4  = __attribute__((ext_vector_type(4))) float;

__device__ __forceinline__ unsigned short f2bf(float x) {
    unsigned u = __float_as_uint(x);
    return (unsigned short)((u + 0x7fffu + ((u >> 16) & 1u)) >> 16);
}

__device__ __forceinline__ unsigned pk2(float lo, float hi) {
    __hip_bfloat162 h = __float22bfloat162_rn(make_float2(lo, hi));
    union { __hip_bfloat162 h; unsigned u; } c; c.h = h;
    return c.u;
}

__device__ __forceinline__ bf16x8 cvt8(float4 f0, float4 f1) {
    union { unsigned u[4]; bf16x8 v; } r;
    r.u[0] = pk2(f0.x, f0.y);
    r.u[1] = pk2(f0.z, f0.w);
    r.u[2] = pk2(f1.x, f1.y);
    r.u[3] = pk2(f1.z, f1.w);
    return r.v;
}

// ordered-float: monotone u32 mapping of f32
__device__ __forceinline__ unsigned ordf(float v) {
    unsigned u = __float_as_uint(v);
    return u ^ ((unsigned)((int)u >> 31) | 0x80000000u);
}

// guarded descending insert into a 4-key list (keys pack value|~idx: tie -> lower idx wins)
__device__ __forceinline__ void insk4(unsigned key, unsigned K[4]) {
    if (key > K[3]) {
        bool b0 = key > K[0], b1 = key > K[1], b2 = key > K[2];
        unsigned k0 = K[0], k1 = K[1], k2 = K[2];
        K[0] = b0 ? key : k0;
        K[1] = b0 ? k0 : (b1 ? key : k1);
        K[2] = b1 ? k1 : (b2 ? key : k2);
        K[3] = b2 ? k2 : key;
    }
}

__device__ __forceinline__ void insk8(unsigned key, unsigned* K) {
    if (key <= K[7]) return;
    #pragma unroll
    for (int k = 0; k < 8; ++k) {
        if (key > K[k]) {
            #pragma unroll
            for (int m = 7; m > k; --m) K[m] = K[m-1];
            K[k] = key;
            return;
        }
    }
}

// exact float top-4 with (value desc, idx asc) tie rule — matches jax.lax.top_k
template<int K>
__device__ __forceinline__ void insK(float v, int c, float* V, int* C) {
    #pragma unroll
    for (int k = 0; k < K; ++k) {
        if (v > V[k] || (v == V[k] && c < C[k])) {
            #pragma unroll
            for (int m = K - 1; m > k; --m) { V[m] = V[m-1]; C[m] = C[m-1]; }
            V[k] = v; C[k] = c;
            return;
        }
    }
}

// ---------------- kernel 1: normalize i_feats + query bf16 fragment image ----------------
// apre element (q, c, g) at index g*2048 + c*128 + q  (16B each): bf16 of
// ihat[q][k], k = c*32 + g*8 .. +8
__global__ void prep_kernel(const float* __restrict__ x, float* __restrict__ ihat,
                            uint4* __restrict__ apre) {
    int r = blockIdx.x;
    int l = threadIdx.x;             // 0..63, owns k = l*8 .. +8  (c = l>>2, g = l&3)
    const float4* row = (const float4*)(x + (size_t)r * D);
    float4 v0 = row[l * 2 + 0];
    float4 v1 = row[l * 2 + 1];
    float s = v0.x*v0.x + v0.y*v0.y + v0.z*v0.z + v0.w*v0.w
            + v1.x*v1.x + v1.y*v1.y + v1.z*v1.z + v1.w*v1.w;
    #pragma unroll
    for (int off = 32; off > 0; off >>= 1) s += __shfl_xor(s, off);
    float inv = 1.0f / sqrtf(s);
    float a0 = v0.x*inv, a1 = v0.y*inv, a2 = v0.z*inv, a3 = v0.w*inv;
    float a4 = v1.x*inv, a5 = v1.y*inv, a6 = v1.z*inv, a7 = v1.w*inv;
    float4* orow = (float4*)(ihat + (size_t)r * D);
    orow[l*2+0] = make_float4(a0, a1, a2, a3);
    orow[l*2+1] = make_float4(a4, a5, a6, a7);
    uint4 p;
    p.x = f2bf(a0) | ((unsigned)f2bf(a1) << 16);
    p.y = f2bf(a2) | ((unsigned)f2bf(a3) << 16);
    p.z = f2bf(a4) | ((unsigned)f2bf(a5) << 16);
    p.w = f2bf(a6) | ((unsigned)f2bf(a7) << 16);
    apre[((l & 3) << 11) + ((l >> 2) << 7) + r] = p;
}

// ---------------- kernel 2: streaming MFMA sim + packed-key top-4, wave-paired ---------
// 8 waves = 4 pairs. Pair pr streams tile t = blockIdx*4+pr (+= NSTR); the two waves
// of a pair (h = wid&1) each cover 64 of the 128 queries (4 MFMA frags). Halves
// per-wave persistent state (acc 16 + keys 16 + pre 32 ~ 95 VGPR < 128 cap) to kill
// the R5-R8 register spill (200+ MB scratch). Duplicate img loads within a pair are
// L1/L2 hits; grid-uniform loop + raw s_barrier per tile (no vmcnt drain) bounds drift.
__global__ __launch_bounds__(512)
void sim_topk(const uint4* __restrict__ apre, const float* __restrict__ img,
              int N, int ntiles, int nit, unsigned* __restrict__ pk)
{
    extern __shared__ __align__(16) unsigned char Bs[];   // 131072 B
    const int tid  = threadIdx.x;
    const int lane = tid & 63;
    const int wid  = tid >> 6;
    const int lr   = lane & 15;
    const int kg   = lane >> 4;
    const int h    = wid & 1;
    const int pr   = wid >> 1;

    // stage query frags -> LDS (one-time): element (q,c,g) at c*8192 + g*2048 + q*16
    #pragma unroll
    for (int j = 0; j < 16; ++j) {
        int s = tid + j * 512;                 // 0..8191
        uint4 p = apre[s];
        int addr = ((s >> 7) & 15) * 8192 + (s >> 11) * 2048 + (s & 127) * 16;
        *(uint4*)(Bs + addr) = p;
    }
    __syncthreads();

    // frag(nf, c) = Bs + c*8192 + lane_off + nf*256 ; q = h*64 + nf*16 + lr
    const int lane_off = kg * 2048 + h * 1024 + lr * 16;

    // per-lane running top-4 keys for 4 queries
    unsigned keys[4][4];
    #pragma unroll
    for (int nf = 0; nf < 4; ++nf)
        #pragma unroll
        for (int s = 0; s < 4; ++s) keys[nf][s] = 0u;

    const int sid = blockIdx.x * 4 + pr;
    int t = sid;
    const float* gp;
    {
        int row = t * 16 + lr;
        if (row >= N) row = N - 1;
        gp = img + (size_t)row * D + kg * 8;
    }

    float4 pre[4][2];
    if (t < ntiles) {
        #pragma unroll
        for (int c = 0; c < 4; ++c) {
            pre[c][0] = *(const float4*)(gp + c * 32);
            pre[c][1] = *(const float4*)(gp + c * 32 + 4);
        }
    }

#define CHUNK(c) do {                                                          \
        float4 f0_ = pre[(c) & 3][0], f1_ = pre[(c) & 3][1];                   \
        if ((c) < 12) {                                                        \
            pre[(c) & 3][0] = *(const float4*)(gp + ((c) + 4) * 32);           \
            pre[(c) & 3][1] = *(const float4*)(gp + ((c) + 4) * 32 + 4);       \
        } else {                                                               \
            pre[(c) & 3][0] = *(const float4*)(gpn + ((c) - 12) * 32);         \
            pre[(c) & 3][1] = *(const float4*)(gpn + ((c) - 12) * 32 + 4);     \
        }                                                                      \
        sq += f0_.x*f0_.x + f0_.y*f0_.y + f0_.z*f0_.z + f0_.w*f0_.w            \
            + f1_.x*f1_.x + f1_.y*f1_.y + f1_.z*f1_.z + f1_.w*f1_.w;           \
        bf16x8 a_ = cvt8(f0_, f1_);                                            \
        const unsigned char* bp_ = Bs + (c) * 8192 + lane_off;                 \
        _Pragma("unroll")                                                      \
        for (int nf_ = 0; nf_ < 4; ++nf_) {                                    \
            bf16x8 b_ = *(const bf16x8*)(bp_ + nf_ * 256);                     \
            acc[nf_] = __builtin_amdgcn_mfma_f32_16x16x32_bf16(a_, b_, acc[nf_], 0, 0, 0); \
        }                                                                      \
    } while (0)

    for (int it = 0; it < nit; ++it) {
        int tn = t + NSTR;
        if (t < ntiles) {
            const float* gpn;
            {
                int tt = (tn < ntiles) ? tn : t;
                int row = tt * 16 + lr;
                if (row >= N) row = N - 1;
                gpn = img + (size_t)row * D + kg * 8;
            }
            f32x4 acc[4];
            #pragma unroll
            for (int nf = 0; nf < 4; ++nf) acc[nf] = (f32x4){0.f, 0.f, 0.f, 0.f};
            float sq = 0.f;

            CHUNK(0);  CHUNK(1);  CHUNK(2);  CHUNK(3);
            CHUNK(4);  CHUNK(5);  CHUNK(6);  CHUNK(7);
            CHUNK(8);  CHUNK(9);  CHUNK(10); CHUNK(11);
            CHUNK(12); CHUNK(13); CHUNK(14); CHUNK(15);

            // row norms: lane's sq covers its row's kg-slices; butterfly over kg lanes
            float s2 = sq;
            s2 += __shfl_xor(s2, 16);
            s2 += __shfl_xor(s2, 32);
            float rnorm = s2 > 0.f ? rsqrtf(s2) : 0.f;

            const int ib = t * 16 + kg * 4;
            #pragma unroll
            for (int g = 0; g < 4; ++g) {
                int idx = ib + g;
                bool ok = idx < N;
                unsigned ic = (unsigned)idx ^ IDXM;
                float r = __shfl(rnorm, kg * 4 + g);
                #pragma unroll
                for (int nf = 0; nf < 4; ++nf) {
                    unsigned o   = ordf(acc[nf][g] * r);
                    unsigned key = ok ? ((o & 0xFFFC0000u) | ic) : 0u;
                    insk4(key, keys[nf]);
                }
            }
            gp = gpn;
        }
        t = tn;
        __builtin_amdgcn_s_barrier();   // raw rendezvous: bounds pair drift, no vmcnt drain
    }
#undef CHUNK

    // merge across the 4 kg lane-groups (same query lives in lanes lr, lr+16, lr+32, lr+48)
    #pragma unroll
    for (int nf = 0; nf < 4; ++nf) {
        #pragma unroll
        for (int st = 0; st < 2; ++st) {
            const int off = st ? 32 : 16;
            unsigned mk[4];
            #pragma unroll
            for (int s = 0; s < 4; ++s) mk[s] = __shfl_xor((int)keys[nf][s], off);
            #pragma unroll
            for (int s = 0; s < 4; ++s) insk4(mk[s], keys[nf]);
        }
    }

    // block-level merge in LDS (query buffer dead now): slot (pr, q), 4 pairs x 128 q
    __syncthreads();
    if (kg == 0) {
        #pragma unroll
        for (int nf = 0; nf < 4; ++nf) {
            int q = h * 64 + nf * 16 + lr;
            uint4 v;
            v.x = keys[nf][0]; v.y = keys[nf][1]; v.z = keys[nf][2]; v.w = keys[nf][3];
            *(uint4*)(Bs + ((size_t)pr * 128 + q) * 16) = v;
        }
    }
    __syncthreads();
    if (tid < BQ) {
        int q = tid;
        unsigned V[4] = {0u, 0u, 0u, 0u};
        #pragma unroll
        for (int w = 0; w < 4; ++w) {
            uint4 kk = *(const uint4*)(Bs + ((size_t)w * 128 + q) * 16);
            insk4(kk.x, V); insk4(kk.y, V); insk4(kk.z, V); insk4(kk.w, V);
        }
        uint4 o; o.x = V[0]; o.y = V[1]; o.z = V[2]; o.w = V[3];
        *(uint4*)(pk + (size_t)q * NB4 + (size_t)blockIdx.x * 4) = o;
    }
}

// ---------------- kernel 3: reduce keys -> top-8 -> exact fp32 rescore -> weights ----
__global__ __launch_bounds__(256)
void reduce_rescore(const unsigned* __restrict__ pk, int nb4,
                    const float* __restrict__ ihat, const float* __restrict__ img, int N,
                    float* __restrict__ swo, int* __restrict__ sidxo,
                    int* __restrict__ valido)
{
    __shared__ unsigned lk[256][8];
    __shared__ float sv[8];
    __shared__ int   si[8];
    const int r = blockIdx.x, tid = threadIdx.x;

    unsigned K[8];
    #pragma unroll
    for (int k = 0; k < 8; ++k) K[k] = 0u;
    const unsigned* prow = pk + (size_t)r * nb4;
    for (int j = tid; j < nb4; j += 256) insk8(prow[j], K);
    #pragma unroll
    for (int k = 0; k < 8; ++k) lk[tid][k] = K[k];
    __syncthreads();
    if (tid < 16) {
        for (int o = 1; o < 16; ++o) {
            int t2 = tid + o * 16;
            #pragma unroll
            for (int s = 0; s < 8; ++s) insk8(lk[t2][s], K);
        }
        #pragma unroll
        for (int k = 0; k < 8; ++k) lk[tid][k] = K[k];
    }
    __syncthreads();
    if (tid == 0) {
        for (int o = 1; o < 16; ++o)
            #pragma unroll
            for (int s = 0; s < 8; ++s) insk8(lk[o][s], K);
        #pragma unroll
        for (int k = 0; k < 8; ++k) {
            int idx = (int)((K[k] & IDXM) ^ IDXM);
            si[k] = (K[k] != 0u && idx < N) ? idx : -1;
        }
    }
    __syncthreads();

    // exact fp32 rescore of the 8 candidates (32 lanes each)
    {
        const int k = tid >> 5, l = tid & 31;
        int idx = si[k];
        float dot = 0.f, ssq = 0.f;
        if (idx >= 0) {
            const float* a = ihat + (size_t)r * D + l * 16;
            const float* b = img + (size_t)idx * D + l * 16;
            #pragma unroll
            for (int j = 0; j < 4; ++j) {
                float4 va = *(const float4*)(a + j*4);
                float4 vb = *(const float4*)(b + j*4);
                dot += va.x*vb.x + va.y*vb.y + va.z*vb.z + va.w*vb.w;
                ssq += vb.x*vb.x + vb.y*vb.y + vb.z*vb.z + vb.w*vb.w;
            }
        }
        #pragma unroll
        for (int o = 16; o > 0; o >>= 1) { dot += __shfl_xor(dot, o); ssq += __shfl_xor(ssq, o); }
        if (l == 0) sv[k] = (idx >= 0 && ssq > 0.f) ? dot * rsqrtf(ssq) : -1e30f;
    }
    __syncthreads();

    if (tid == 0) {
        float Vt[4]; int Ct[4];
        #pragma unroll
        for (int k = 0; k < 4; ++k) { Vt[k] = -1e30f; Ct[k] = SENT; }
        #pragma unroll
        for (int k = 0; k < 8; ++k)
            if (si[k] >= 0) insK<4>(sv[k], si[k], Vt, Ct);
        float lg[4]; int vd[3];
        lg[0] = SSCALE;
        #pragma unroll
        for (int k = 0; k < 3; ++k) {
            vd[k] = (Vt[k+1] > THR) ? 1 : 0;
            lg[k+1] = vd[k] ? SSCALE * Vt[k+1] : -1e30f;
        }
        float m = fmaxf(fmaxf(lg[0], lg[1]), fmaxf(lg[2], lg[3]));
        float e0 = expf(lg[0]-m), e1 = expf(lg[1]-m), e2 = expf(lg[2]-m), e3 = expf(lg[3]-m);
        float sum = e0 + e1 + e2 + e3;
        float ee[3] = {e1, e2, e3};
        #pragma unroll
        for (int k = 0; k < 3; ++k) {
            float w = 1.0f - ee[k] / sum;
            swo[r*3+k]    = vd[k] ? w : 0.0f;
            sidxo[r*3+k]  = vd[k] ? Ct[k+1] : 0;
            valido[r*3+k] = vd[k];
        }
    }
}

// ---------------- kernel 4: assemble output (1536 x 512 fp32) ----------------
__global__ void assemble_kernel(const float* __restrict__ i_feats, const float* __restrict__ t_feats,
                                const float* __restrict__ img, const float* __restrict__ txt,
                                const float* __restrict__ sw, const int* __restrict__ sidx,
                                const int* __restrict__ valid, float* __restrict__ out)
{
    const int r = blockIdx.x;      // 0..1535
    const int t = threadIdx.x;     // 0..127
    float4* orow = (float4*)(out + (size_t)r * D);
    if (r < 128) {
        orow[t] = ((const float4*)(i_feats + (size_t)r * D))[t];
    } else if (r < 512) {
        int s = r - 128;
        float4 v = make_float4(0.f,0.f,0.f,0.f);
        if (valid[s]) v = ((const float4*)(img + (size_t)sidx[s] * D))[t];
        orow[t] = v;
    } else if (r < 640) {
        orow[t] = ((const float4*)(t_feats + (size_t)(r - 512) * D))[t];
    } else if (r < 1024) {
        int s = r - 640;
        float4 v = make_float4(0.f,0.f,0.f,0.f);
        if (valid[s]) v = ((const float4*)(txt + (size_t)sidx[s] * D))[t];
        orow[t] = v;
    } else {
        int li = r - 1024;
        float o[4];
        int j0 = t * 4;
        if (li < 128) {
            #pragma unroll
            for (int u = 0; u < 4; ++u) {
                int j = j0 + u;
                if (j < 128) o[u] = (j == li) ? 1.0f : 0.0f;
                else {
                    int s = j - 128;
                    o[u] = (s / 3 == li) ? sw[li*3 + (s % 3)] : 0.0f;
                }
            }
        } else {
            int i2 = li - 128;
            int b = i2 / 3;
            int vi = valid[i2];
            #pragma unroll
            for (int u = 0; u < 4; ++u) {
                int j = j0 + u;
                float val;
                if (j < 128) val = (vi && j == b) ? 1.0f : 0.0f;
                else {
                    int s2 = j - 128;
                    int vj = valid[s2];
                    int b2 = s2 / 3;
                    if (vi && vj)        val = (b == b2) ? 1.0f : 0.0f;
                    else if (!vi && !vj) val = (i2 == s2) ? 1.0f : 0.0f;
                    else                 val = 0.0f;
                }
                o[u] = val;
            }
        }
        orow[t] = make_float4(o[0], o[1], o[2], o[3]);
    }
}

extern "C" void kernel_launch(void* const* d_in, const int* in_sizes, int n_in,
                              void* d_out, int out_size, void* d_ws, size_t ws_size,
                              hipStream_t stream) {
    const float* i_feats = (const float*)d_in[0];
    const float* t_feats = (const float*)d_in[1];
    const float* img     = (const float*)d_in[2];
    const float* txt     = (const float*)d_in[3];
    float* out = (float*)d_out;

    const int N      = in_sizes[2] / D;        // 200000
    const int ntiles = (N + 15) / 16;          // 12500
    const int nit    = (ntiles + NSTR - 1) / NSTR;   // 13

    char* ws = (char*)d_ws;
    size_t off = 0;
    float*    ihat = (float*)(ws + off);    off += (size_t)BQ * D * 4;    // 256 KB
    uint4*    apre = (uint4*)(ws + off);    off += (size_t)BQ * D * 2;    // 128 KB
    unsigned* pk   = (unsigned*)(ws + off); off += (size_t)BQ * NB4 * 4;  // 512 KB
    float*    swv  = (float*)(ws + off);    off += BQ * 4 * 4;
    int*      sidx = (int*)(ws + off);      off += BQ * 4 * 4;
    int*      vld  = (int*)(ws + off);      off += BQ * 4 * 4;

    prep_kernel<<<BQ, 64, 0, stream>>>(i_feats, ihat, apre);
    sim_topk<<<NBLK, 512, 131072, stream>>>(apre, img, N, ntiles, nit, pk);
    reduce_rescore<<<BQ, 256, 0, stream>>>(pk, NB4, ihat, img, N, swv, sidx, vld);
    assemble_kernel<<<3 * (BQ + BQ * KK), 128, 0, stream>>>(i_feats, t_feats, img, txt,
                                                            swv, sidx, vld, out);
}